// Round 32
// baseline (480.382 us; speedup 1.0000x reference)
//
#include <hip/hip_runtime.h>
#include <hip/hip_bf16.h>

// Money_former MLA DINT — round 32: r31 base (479.7 us) + wave-packing of
// tiny kernels (same proven low-risk class):
//   k_rmsnorm2_b -> wave-per-row, grid (514,2), no LDS/sync
//   k_gwv        -> 4 waves/block, grid (257,2)
//   k_chunksum   -> 4 waves/block, grid (17,2)
// T=2056, D=512, 2 layers, 16 logical heads (8 pairs) of 48.

#define Tn 2056
#define LPn 257
#define Dn 512
#define TP 2112   // padded T (33*64)
#define NQ 6      // jt quarters
#define WP 3866624  // weight params per layer (see cvtw segment map)
#define CVB 3776    // cvt blocks = WP/4/256

static constexpr float SC_LOG2E  = 0.20822625044783914f;   // 48^-0.5 * log2(e)
static constexpr float MSHIFT    = 32.0f;                  // fixed softmax shift (base-2)
static constexpr float EPS_C     = 1.1920928955078125e-07f;

typedef float f32x4 __attribute__((ext_vector_type(4)));
typedef short bf16x8 __attribute__((ext_vector_type(8)));
typedef unsigned short u16x8 __attribute__((ext_vector_type(8)));

__device__ __forceinline__ float fexp2(float x) { return __builtin_amdgcn_exp2f(x); }

__device__ __forceinline__ unsigned short f2bu(float f) {
  __hip_bfloat16 h = __float2bfloat16(f);
  return *reinterpret_cast<unsigned short*>(&h);
}

// fully-masked (i-block, j-tile) test: 64-run mod 257 min/max
__device__ __forceinline__ bool tile_masked(int bm, int jt) {
  int jstart = (jt * 64) % LPn;
  int jmin = (jstart + 63 >= LPn) ? 0 : jstart;
  int istart = bm % LPn;
  int imax = (istart + 63 >= LPn) ? (LPn - 1) : (istart + 63);
  return jmin > imax;
}

// per-block inline lambda
__device__ __forceinline__ float calc_lam(const float* lq1, const float* lk1,
                                          const float* lq2, const float* lk2,
                                          float lamc) {
  float d1 = 0.f, d2 = 0.f;
#pragma unroll
  for (int k = 0; k < 32; k++) { d1 = fmaf(lq1[k], lk1[k], d1); d2 = fmaf(lq2[k], lk2[k], d2); }
  return __expf(d1) - __expf(d2) + lamc;
}

// ---------------- weight convert body: 7 segments -> contiguous bf16 arena ----------------
// layout (elements): [kvd 160x512 | qd 192x512 | kvu 1024x128 | qu 768x192 |
//                     oW 512x512 | ffi 4096x512 | ffo 512x2048]
// boundaries: 81920, 180224, 311296, 458752, 720896, 2818048, 3866624 (=WP)
__device__ __forceinline__ void cvtw_body(int vid, int tid,
                                          const float* __restrict__ kvd,
                                          const float* __restrict__ qd,
                                          const float* __restrict__ kvu,
                                          const float* __restrict__ qu,
                                          const float* __restrict__ oW,
                                          const float* __restrict__ ffi,
                                          const float* __restrict__ ffo,
                                          __hip_bfloat16* __restrict__ out) {
  size_t i = ((size_t)vid * 256 + tid) * 4;
  if (i >= (size_t)WP) return;
  size_t r = i;
  const float* src;
  if      (r <   81920) { src = kvd + r; }
  else if (r <  180224) { src = qd  + (r - 81920); }
  else if (r <  311296) { src = kvu + (r - 180224); }
  else if (r <  458752) { src = qu  + (r - 311296); }
  else if (r <  720896) { src = oW  + (r - 458752); }
  else if (r < 2818048) { src = ffi + (r - 720896); }
  else                  { src = ffo + (r - 2818048); }
  f32x4 v = *reinterpret_cast<const f32x4*>(src);
  unsigned short o4[4];
#pragma unroll
  for (int e = 0; e < 4; e++) o4[e] = f2bu(v[e]);
  *reinterpret_cast<uint2*>((unsigned short*)out + i) = *reinterpret_cast<const uint2*>(o4);
}

// ---------------- sentinel ----------------
__global__ __launch_bounds__(256) void k_fill42(float* __restrict__ out, int n) {
  int i = blockIdx.x * 256 + threadIdx.x;
  if (i < n) out[i] = 42.0f;
}

// ---------------- RoPE tables ----------------
__global__ __launch_bounds__(256) void k_freqs(float* __restrict__ cosb, float* __restrict__ sinb) {
  int idx = blockIdx.x * 256 + threadIdx.x;
  if (idx >= 256 * 8) return;
  int pos = idx >> 3, j = idx & 7;
  float fb = powf(10000.f, -(float)j * 0.125f);            // 1/10000^(j/8)
  float ramp = fminf(fmaxf((float)j * 0.25f, 0.f), 1.f);   // low=0, high=4
  float sm = 1.f - ramp;
  float fr = fb * (1.f / 40.f) * (1.f - sm) + fb * sm;
  float ang = (float)pos * fr;
  cosb[idx] = cosf(ang);
  sinb[idx] = sinf(ang);
}

// ---------------- Embedding ----------------
__global__ __launch_bounds__(256) void k_embed(const float* __restrict__ x,
                                               const float* __restrict__ ticker_emb,
                                               const float* __restrict__ sep_emb,
                                               const float* __restrict__ shared_W,
                                               const float* __restrict__ unique_W,
                                               const int* __restrict__ sep_idx,
                                               const int* __restrict__ tickers,
                                               float* __restrict__ h) {
  int t = blockIdx.x;
  int c = blockIdx.y * 256 + threadIdx.x;
  int l = t >> 3, s = t & 7;
  float val;
  if (l == 0) {
    val = sep_emb[sep_idx[0] * Dn + c];
  } else {
    const float* xr = x + ((size_t)(l - 1) * 8 + s) * 32;
    const float* w = (c < 384) ? (shared_W + (size_t)c * 32)
                               : (unique_W + ((size_t)s * 128 + (c - 384)) * 32);
    float acc = 0.f;
#pragma unroll
    for (int f = 0; f < 32; f++) acc = fmaf(xr[f], w[f], acc);
    val = acc;
  }
  val += ticker_emb[(size_t)tickers[s] * Dn + c];
  h[(size_t)t * Dn + c] = val;
}

// ---------------- merged: x < Tn -> rmsnorm512 (h->xnb bf16) ; else -> cvtw ----------------
__global__ __launch_bounds__(256) void k_rms_cvt(const float* __restrict__ in,
                                                 const float* __restrict__ w,
                                                 __hip_bfloat16* __restrict__ out,
                                                 const float* __restrict__ kvd,
                                                 const float* __restrict__ qd,
                                                 const float* __restrict__ kvu,
                                                 const float* __restrict__ qu,
                                                 const float* __restrict__ oW,
                                                 const float* __restrict__ ffi,
                                                 const float* __restrict__ ffo,
                                                 __hip_bfloat16* __restrict__ wout) {
  __shared__ float red[4];
  if (blockIdx.x >= Tn) {
    cvtw_body(blockIdx.x - Tn, threadIdx.x, kvd, qd, kvu, qu, oW, ffi, ffo, wout);
    return;
  }
  int row = blockIdx.x;
  const float* xr = in + (size_t)row * 512;
  float ss = 0.f;
  for (int c = threadIdx.x; c < 512; c += 256) { float v = xr[c]; ss = fmaf(v, v, ss); }
  for (int off = 1; off < 64; off <<= 1) ss += __shfl_xor(ss, off);
  if ((threadIdx.x & 63) == 0) red[threadIdx.x >> 6] = ss;
  __syncthreads();
  float tot = red[0] + red[1] + red[2] + red[3];
  float scale = rsqrtf(tot * (1.f / 512.f) + EPS_C);
  for (int c = threadIdx.x; c < 512; c += 256)
    out[(size_t)row * 512 + c] = __float2bfloat16(xr[c] * scale * w[c]);
}

// ---------------- dual RMSNorm, wave-per-row: y==0 ckv(128,str160), y==1 qlat(192,str192) ----------------
// grid (Tn/4, 2), 256 threads; wave w handles row = bx*4 + w entirely in-register.
__global__ __launch_bounds__(256) void k_rmsnorm2_b(const float* __restrict__ ckv,
                                                    const float* __restrict__ qlat,
                                                    const float* __restrict__ kvnw,
                                                    const float* __restrict__ qnw,
                                                    __hip_bfloat16* __restrict__ ckvnb,
                                                    __hip_bfloat16* __restrict__ qlatnb) {
  int wave = threadIdx.x >> 6, lane = threadIdx.x & 63;
  int row = blockIdx.x * 4 + wave;
  const float* xr; const float* w; __hip_bfloat16* out; int ncols;
  if (blockIdx.y == 0) { xr = ckv + (size_t)row * 160;  w = kvnw; out = ckvnb + (size_t)row * 128;  ncols = 128; }
  else                 { xr = qlat + (size_t)row * 192; w = qnw;  out = qlatnb + (size_t)row * 192; ncols = 192; }
  float ss = 0.f;
  for (int c = lane; c < ncols; c += 64) { float v = xr[c]; ss = fmaf(v, v, ss); }
  for (int off = 1; off < 64; off <<= 1) ss += __shfl_xor(ss, off);
  float scale = rsqrtf(ss / (float)ncols + EPS_C);
  for (int c = lane; c < ncols; c += 64)
    out[c] = __float2bfloat16(xr[c] * scale * w[c]);
}

// ---------------- fused: h += sum(pp parts) ; xnb = rmsnorm(h)*w (bf16 out) ----------------
__global__ __launch_bounds__(256) void k_addred_rms_b(float* __restrict__ h,
                                                      const float* __restrict__ pp,
                                                      const float* __restrict__ w,
                                                      __hip_bfloat16* __restrict__ out,
                                                      int nsplit) {
  int row = blockIdx.x;
  long n = (long)Tn * 512;
  float v[2];
  float ss = 0.f;
#pragma unroll
  for (int cc = 0; cc < 2; cc++) {
    int c = threadIdx.x + cc * 256;
    long idx = (long)row * 512 + c;
    float s = h[idx];
    for (int k = 0; k < nsplit; k++) s += pp[(size_t)k * n + idx];
    h[idx] = s;
    v[cc] = s;
    ss = fmaf(s, s, ss);
  }
  for (int off = 1; off < 64; off <<= 1) ss += __shfl_xor(ss, off);
  __shared__ float red[4];
  if ((threadIdx.x & 63) == 0) red[threadIdx.x >> 6] = ss;
  __syncthreads();
  float tot = red[0] + red[1] + red[2] + red[3];
  float scale = rsqrtf(tot * (1.f / 512.f) + EPS_C);
#pragma unroll
  for (int cc = 0; cc < 2; cc++) {
    int c = threadIdx.x + cc * 256;
    out[(size_t)row * 512 + c] = __float2bfloat16(v[cc] * scale * w[c]);
  }
}

// ---------------- merged: x < Tn -> addred_rms_b(nsplit=4) ; else -> cvtw (next layer) ----------------
__global__ __launch_bounds__(256) void k_addred_rms_cvt(float* __restrict__ h,
                                                        const float* __restrict__ pp,
                                                        const float* __restrict__ w,
                                                        __hip_bfloat16* __restrict__ out,
                                                        const float* __restrict__ kvd,
                                                        const float* __restrict__ qd,
                                                        const float* __restrict__ kvu,
                                                        const float* __restrict__ qu,
                                                        const float* __restrict__ oW,
                                                        const float* __restrict__ ffi,
                                                        const float* __restrict__ ffo,
                                                        __hip_bfloat16* __restrict__ wout) {
  __shared__ float red[4];
  if (blockIdx.x >= Tn) {
    cvtw_body(blockIdx.x - Tn, threadIdx.x, kvd, qd, kvu, qu, oW, ffi, ffo, wout);
    return;
  }
  int row = blockIdx.x;
  long n = (long)Tn * 512;
  float v[2];
  float ss = 0.f;
#pragma unroll
  for (int cc = 0; cc < 2; cc++) {
    int c = threadIdx.x + cc * 256;
    long idx = (long)row * 512 + c;
    float s = h[idx];
    for (int k = 0; k < 4; k++) s += pp[(size_t)k * n + idx];
    h[idx] = s;
    v[cc] = s;
    ss = fmaf(s, s, ss);
  }
  for (int off = 1; off < 64; off <<= 1) ss += __shfl_xor(ss, off);
  if ((threadIdx.x & 63) == 0) red[threadIdx.x >> 6] = ss;
  __syncthreads();
  float tot = red[0] + red[1] + red[2] + red[3];
  float scale = rsqrtf(tot * (1.f / 512.f) + EPS_C);
#pragma unroll
  for (int cc = 0; cc < 2; cc++) {
    int c = threadIdx.x + cc * 256;
    out[(size_t)row * 512 + c] = __float2bfloat16(v[cc] * scale * w[c]);
  }
}

// ---------------- fused: h += sum(pp parts) ; zfin = rmsnorm(h)*w (f32 out) ----------------
__global__ __launch_bounds__(256) void k_addred_rms_f(float* __restrict__ h,
                                                      const float* __restrict__ pp,
                                                      const float* __restrict__ w,
                                                      float* __restrict__ out,
                                                      int nsplit) {
  int row = blockIdx.x;
  long n = (long)Tn * 512;
  float v[2];
  float ss = 0.f;
#pragma unroll
  for (int cc = 0; cc < 2; cc++) {
    int c = threadIdx.x + cc * 256;
    long idx = (long)row * 512 + c;
    float s = h[idx];
    for (int k = 0; k < nsplit; k++) s += pp[(size_t)k * n + idx];
    h[idx] = s;
    v[cc] = s;
    ss = fmaf(s, s, ss);
  }
  for (int off = 1; off < 64; off <<= 1) ss += __shfl_xor(ss, off);
  __shared__ float red[4];
  if ((threadIdx.x & 63) == 0) red[threadIdx.x >> 6] = ss;
  __syncthreads();
  float tot = red[0] + red[1] + red[2] + red[3];
  float scale = rsqrtf(tot * (1.f / 512.f) + EPS_C);
#pragma unroll
  for (int cc = 0; cc < 2; cc++) {
    int c = threadIdx.x + cc * 256;
    out[(size_t)row * 512 + c] = v[cc] * scale * w[c];
  }
}

// ---------------- paired GEMM: z=0 (A0,B0,C0,N0,K0), z=1 (A1,B1,C1,N1,K1) ----------------
__global__ __launch_bounds__(256) void k_gemm64_pair(const __hip_bfloat16* __restrict__ A0,
                                                     const __hip_bfloat16* __restrict__ B0,
                                                     float* __restrict__ C0, int N0, int K0,
                                                     const __hip_bfloat16* __restrict__ A1,
                                                     const __hip_bfloat16* __restrict__ B1,
                                                     float* __restrict__ C1, int N1, int K1) {
  __shared__ unsigned short Als[64][40];
  __shared__ unsigned short Bls[64][40];
  const __hip_bfloat16* A; const __hip_bfloat16* B; float* C; int N, K;
  if (blockIdx.z == 0) { A = A0; B = B0; C = C0; N = N0; K = K0; }
  else                 { A = A1; B = B1; C = C1; N = N1; K = K1; }
  int bm = blockIdx.y * 64, bn = blockIdx.x * 64;
  if (bn >= N) return;                       // uniform per-block early exit
  int tid = threadIdx.x;
  int wave = tid >> 6, lane = tid & 63;
  int lrow = lane & 15, lgrp = lane >> 4;
  f32x4 acc[4] = {};
  for (int k0 = 0; k0 < K; k0 += 32) {
    {
      int row = tid >> 2, cg = tid & 3;
      u16x8 v = {0, 0, 0, 0, 0, 0, 0, 0};
      if (bm + row < Tn)
        v = *reinterpret_cast<const u16x8*>(A + (size_t)(bm + row) * K + k0 + cg * 8);
      *reinterpret_cast<u16x8*>(&Als[row][cg * 8]) = v;
    }
    {
      int row = tid >> 2, cg = tid & 3;
      u16x8 v = {0, 0, 0, 0, 0, 0, 0, 0};
      if (bn + row < N)
        v = *reinterpret_cast<const u16x8*>(B + (size_t)(bn + row) * K + k0 + cg * 8);
      *reinterpret_cast<u16x8*>(&Bls[row][cg * 8]) = v;
    }
    __syncthreads();
    bf16x8 af = *reinterpret_cast<const bf16x8*>(&Als[wave * 16 + lrow][lgrp * 8]);
    bf16x8 bfr[4];
#pragma unroll
    for (int ni = 0; ni < 4; ni++)
      bfr[ni] = *reinterpret_cast<const bf16x8*>(&Bls[ni * 16 + lrow][lgrp * 8]);
#pragma unroll
    for (int ni = 0; ni < 4; ni++)
      acc[ni] = __builtin_amdgcn_mfma_f32_16x16x32_bf16(af, bfr[ni], acc[ni], 0, 0, 0);
    __syncthreads();
  }
#pragma unroll
  for (int ni = 0; ni < 4; ni++)
#pragma unroll
    for (int r = 0; r < 4; r++) {
      int row = bm + wave * 16 + lgrp * 4 + r;
      int col = bn + ni * 16 + lrow;
      if (row < Tn && col < N)
        C[(size_t)row * N + col] = acc[ni][r];
    }
}

// ---------------- dual GEMM: [ckv | qlat] = xnb @ (wkvd||wqd)^T, N=352, K=512 ----------------
__global__ __launch_bounds__(256) void k_gemm64_dual(const __hip_bfloat16* __restrict__ A,
                                                     const __hip_bfloat16* __restrict__ B,
                                                     float* __restrict__ ckv,
                                                     float* __restrict__ qlat) {
  __shared__ unsigned short Als[64][40];
  __shared__ unsigned short Bls[64][40];
  int bm = blockIdx.y * 64, bn = blockIdx.x * 64;
  int tid = threadIdx.x;
  int wave = tid >> 6, lane = tid & 63;
  int lrow = lane & 15, lgrp = lane >> 4;
  f32x4 acc[4] = {};
  for (int k0 = 0; k0 < 512; k0 += 32) {
    {
      int row = tid >> 2, cg = tid & 3;
      u16x8 v = {0, 0, 0, 0, 0, 0, 0, 0};
      if (bm + row < Tn)
        v = *reinterpret_cast<const u16x8*>(A + (size_t)(bm + row) * 512 + k0 + cg * 8);
      *reinterpret_cast<u16x8*>(&Als[row][cg * 8]) = v;
    }
    {
      int row = tid >> 2, cg = tid & 3;
      u16x8 v = {0, 0, 0, 0, 0, 0, 0, 0};
      if (bn + row < 352)
        v = *reinterpret_cast<const u16x8*>(B + (size_t)(bn + row) * 512 + k0 + cg * 8);
      *reinterpret_cast<u16x8*>(&Bls[row][cg * 8]) = v;
    }
    __syncthreads();
    bf16x8 af = *reinterpret_cast<const bf16x8*>(&Als[wave * 16 + lrow][lgrp * 8]);
    bf16x8 bfr[4];
#pragma unroll
    for (int ni = 0; ni < 4; ni++)
      bfr[ni] = *reinterpret_cast<const bf16x8*>(&Bls[ni * 16 + lrow][lgrp * 8]);
#pragma unroll
    for (int ni = 0; ni < 4; ni++)
      acc[ni] = __builtin_amdgcn_mfma_f32_16x16x32_bf16(af, bfr[ni], acc[ni], 0, 0, 0);
    __syncthreads();
  }
#pragma unroll
  for (int ni = 0; ni < 4; ni++)
#pragma unroll
    for (int r = 0; r < 4; r++) {
      int row = bm + wave * 16 + lgrp * 4 + r;
      int col = bn + ni * 16 + lrow;
      if (row < Tn) {
        if (col < 160)      ckv [(size_t)row * 160 + col]         = acc[ni][r];
        else if (col < 352) qlat[(size_t)row * 192 + (col - 160)] = acc[ni][r];
      }
    }
}

// ---------------- K-split 64x64 MFMA GEMM -> partial buffer pp[kc] (bf16 B) ----------------
__global__ __launch_bounds__(256) void k_gemm64p(const __hip_bfloat16* __restrict__ A,
                                                 const __hip_bfloat16* __restrict__ B,
                                                 float* __restrict__ pp,
                                                 int M, int N, int kchunk) {
  __shared__ unsigned short Als[64][40];
  __shared__ unsigned short Bls[64][40];
  int bm = blockIdx.y * 64, bn = blockIdx.x * 64;
  int kc = blockIdx.z;
  int K = kchunk * gridDim.z;
  int kbase = kc * kchunk;
  int tid = threadIdx.x;
  int wave = tid >> 6, lane = tid & 63;
  int lrow = lane & 15, lgrp = lane >> 4;
  f32x4 acc[4] = {};
  for (int k0 = kbase; k0 < kbase + kchunk; k0 += 32) {
    {
      int row = tid >> 2, cg = tid & 3;
      u16x8 v = {0, 0, 0, 0, 0, 0, 0, 0};
      if (bm + row < M)
        v = *reinterpret_cast<const u16x8*>(A + (size_t)(bm + row) * K + k0 + cg * 8);
      *reinterpret_cast<u16x8*>(&Als[row][cg * 8]) = v;
    }
    {
      int row = tid >> 2, cg = tid & 3;
      u16x8 v = {0, 0, 0, 0, 0, 0, 0, 0};
      if (bn + row < N)
        v = *reinterpret_cast<const u16x8*>(B + (size_t)(bn + row) * K + k0 + cg * 8);
      *reinterpret_cast<u16x8*>(&Bls[row][cg * 8]) = v;
    }
    __syncthreads();
    bf16x8 af = *reinterpret_cast<const bf16x8*>(&Als[wave * 16 + lrow][lgrp * 8]);
    bf16x8 bfr[4];
#pragma unroll
    for (int ni = 0; ni < 4; ni++)
      bfr[ni] = *reinterpret_cast<const bf16x8*>(&Bls[ni * 16 + lrow][lgrp * 8]);
#pragma unroll
    for (int ni = 0; ni < 4; ni++)
      acc[ni] = __builtin_amdgcn_mfma_f32_16x16x32_bf16(af, bfr[ni], acc[ni], 0, 0, 0);
    __syncthreads();
  }
#pragma unroll
  for (int ni = 0; ni < 4; ni++)
#pragma unroll
    for (int r = 0; r < 4; r++) {
      int row = bm + wave * 16 + lgrp * 4 + r;
      int col = bn + ni * 16 + lrow;
      if (row < M && col < N)
        pp[(size_t)kc * M * N + (size_t)row * N + col] = acc[ni][r];
    }
}

// ---------------- Fused FFN-in + SwiGLU (bf16 B) ----------------
__global__ __launch_bounds__(256) void k_ffn(const __hip_bfloat16* __restrict__ A,
                                             const __hip_bfloat16* __restrict__ Bw,
                                             __hip_bfloat16* __restrict__ gatedb) {
  __shared__ unsigned short Als[128][40];
  __shared__ unsigned short Bls[128][40];
  int bm = blockIdx.y * 128, bn = blockIdx.x * 64;
  int tid = threadIdx.x;
  int wave = tid >> 6, lane = tid & 63;
  int lrow = lane & 15, lgrp = lane >> 4;
  f32x4 acc[2][8] = {};
  for (int k0 = 0; k0 < 512; k0 += 32) {
#pragma unroll
    for (int i = 0; i < 2; i++) {
      int vecIdx = tid + i * 256;
      int row = vecIdx >> 2, cg = vecIdx & 3;
      u16x8 v = {0, 0, 0, 0, 0, 0, 0, 0};
      if (bm + row < Tn)
        v = *reinterpret_cast<const u16x8*>(A + (size_t)(bm + row) * 512 + k0 + cg * 8);
      *reinterpret_cast<u16x8*>(&Als[row][cg * 8]) = v;
    }
#pragma unroll
    for (int i = 0; i < 2; i++) {
      int vecIdx = tid + i * 256;
      int row = vecIdx >> 2, cg = vecIdx & 3;
      int grow = (row < 64) ? (bn + row) : (2048 + bn + (row - 64));
      u16x8 v = *reinterpret_cast<const u16x8*>(Bw + (size_t)grow * 512 + k0 + cg * 8);
      *reinterpret_cast<u16x8*>(&Bls[row][cg * 8]) = v;
    }
    __syncthreads();
    bf16x8 af[2], bfr[8];
#pragma unroll
    for (int mi = 0; mi < 2; mi++)
      af[mi] = *reinterpret_cast<const bf16x8*>(&Als[wave * 32 + mi * 16 + lrow][lgrp * 8]);
#pragma unroll
    for (int ni = 0; ni < 8; ni++)
      bfr[ni] = *reinterpret_cast<const bf16x8*>(&Bls[ni * 16 + lrow][lgrp * 8]);
#pragma unroll
    for (int mi = 0; mi < 2; mi++)
#pragma unroll
      for (int ni = 0; ni < 8; ni++)
        acc[mi][ni] = __builtin_amdgcn_mfma_f32_16x16x32_bf16(af[mi], bfr[ni], acc[mi][ni], 0, 0, 0);
    __syncthreads();
  }
#pragma unroll
  for (int mi = 0; mi < 2; mi++)
#pragma unroll
    for (int ni = 0; ni < 4; ni++)
#pragma unroll
      for (int r = 0; r < 4; r++) {
        int row = bm + wave * 32 + mi * 16 + lgrp * 4 + r;
        int col = bn + ni * 16 + lrow;
        if (row < Tn) {
          float u = acc[mi][ni][r];
          float vv = acc[mi][ni + 4][r];
          float sv = vv / (1.f + __expf(-vv));
          gatedb[(size_t)row * 2048 + col] = __float2bfloat16(u * sv);
        }
      }
}

// ---------------- merged: x < Tn -> q/k assemble ; else -> V transpose ----------------
__global__ __launch_bounds__(256) void k_qkv_vt(const float* __restrict__ qf,
                                                const float* __restrict__ kvb,
                                                const float* __restrict__ ckv,
                                                const float* __restrict__ cosb,
                                                const float* __restrict__ sinb,
                                                __hip_bfloat16* __restrict__ qhb,
                                                __hip_bfloat16* __restrict__ khb,
                                                __hip_bfloat16* __restrict__ vtb) {
  __shared__ float tile[64][65];
  if (blockIdx.x < Tn) {
    // ---- q/k assemble (partial RoPE, bf16 out); q pre-scaled ----
    int t = blockIdx.x;
    int l = t >> 3;
    for (int idx = threadIdx.x; idx < 768; idx += 256) {
      int hh = idx / 48, dc = idx % 48;
      int hd = hh >> 1, e = hh & 1;
      float qv, kvv;
      if (dc < 32) {
        qv  = qf [(size_t)t * 768  + hd * 96  + e * 32 + dc];
        kvv = kvb[(size_t)t * 1024 + hd * 128 + e * 32 + dc];
      } else {
        int rj = dc - 32;            // 0..15
        int p = rj >> 1; int isim = rj & 1;
        float xr_q = qf[(size_t)t * 768 + hd * 96 + 64 + e * 16 + p * 2];
        float xi_q = qf[(size_t)t * 768 + hd * 96 + 64 + e * 16 + p * 2 + 1];
        float xr_k = ckv[(size_t)t * 160 + 128 + e * 16 + p * 2];
        float xi_k = ckv[(size_t)t * 160 + 128 + e * 16 + p * 2 + 1];
        if (l == 0) {
          qv  = isim ? xi_q : xr_q;
          kvv = isim ? xi_k : xr_k;
        } else {
          float c = cosb[(l - 1) * 8 + p], s = sinb[(l - 1) * 8 + p];
          if (!isim) { qv = xr_q * c - xi_q * s; kvv = xr_k * c - xi_k * s; }
          else       { qv = xr_q * s + xi_q * c; kvv = xr_k * s + xi_k * c; }
        }
      }
      qhb[(size_t)t * 768 + idx] = __float2bfloat16(qv * SC_LOG2E);   // fold scaling*log2e
      khb[(size_t)t * 768 + idx] = __float2bfloat16(kvv);
    }
  } else {
    // ---- V transpose: vtb[c][t] bf16 ----
    int vid = blockIdx.x - Tn;     // 0..263
    int tt = vid % 33, ct = vid / 33;
    int tid = threadIdx.x;
#pragma unroll
    for (int rep = 0; rep < 16; rep++) {
      int idx = rep * 256 + tid;
      int tr = idx >> 6, cc = idx & 63;
      int t = tt * 64 + tr;
      tile[tr][cc] = (t < Tn) ? kvb[(size_t)t * 1024 + ct * 128 + 64 + cc] : 0.f;
    }
    __syncthreads();
#pragma unroll
    for (int rep = 0; rep < 16; rep++) {
      int idx = rep * 256 + tid;
      int cr = idx >> 6, tc = idx & 63;
      int t = tt * 64 + tc;
      if (t < Tn)
        vtb[(size_t)(ct * 64 + cr) * Tn + t] = __float2bfloat16(tile[tc][cr]);
    }
  }
}

// ---------------- load one Q fragment pair from global (pad cols >=48 are 0) ----------------
__device__ __forceinline__ void load_qfrag(const __hip_bfloat16* qhb, int qrow, int hh,
                                           int lgrp, bf16x8* qf) {
#pragma unroll
  for (int ks = 0; ks < 2; ks++) {
    int co = ks * 32 + lgrp * 8;
    bf16x8 v = {0, 0, 0, 0, 0, 0, 0, 0};
    if (qrow < Tn && co < 48)
      v = *reinterpret_cast<const bf16x8*>(qhb + (size_t)qrow * 768 + hh * 48 + co);
    qf[ks] = v;
  }
}

// ---------------- attention pass 1: per-lane l-sum, single end reduce ----------------
// grid (33, 8, NQ). lsum[(hf*16+hh)*TP + i] = sum_j 2^(s_ij - 32) over this quarter.
__global__ __launch_bounds__(256) void k_attn_pass1(const __hip_bfloat16* __restrict__ qhb,
                                                    const __hip_bfloat16* __restrict__ khb,
                                                    float* __restrict__ lsum) {
  __shared__ unsigned short K1s[64][68];
  __shared__ unsigned short K2s[64][68];
  int bm = blockIdx.x * 64, p = blockIdx.y, hf = blockIdx.z;
  int jt0 = hf * 6, jt1 = min(33, jt0 + 6);
  int hh1 = 2 * p, hh2 = 2 * p + 1;
  int tid = threadIdx.x;
  int wave = tid >> 6, lane = tid & 63;
  int lrow = lane & 15, lgrp = lane >> 4;
  bf16x8 qf1[2], qf2[2];
  int qrow = bm + wave * 16 + lrow;
  load_qfrag(qhb, qrow, hh1, lgrp, qf1);
  load_qfrag(qhb, qrow, hh2, lgrp, qf2);
  float l1r[4], l2r[4];
  int irow[4], imodr[4];
#pragma unroll
  for (int r = 0; r < 4; r++) {
    l1r[r] = 0.f; l2r[r] = 0.f;
    irow[r] = bm + wave * 16 + lgrp * 4 + r;
    imodr[r] = irow[r] % LPn;
  }

  for (int jt = jt0; jt < jt1; jt++) {
    if (tile_masked(bm, jt)) continue;
    __syncthreads();
#pragma unroll
    for (int i = 0; i < 2; i++) {
      int vecIdx = tid + i * 256;
      int row = vecIdx >> 3, cg = vecIdx & 7;
      u16x8 v1 = {0, 0, 0, 0, 0, 0, 0, 0}, v2 = v1;
      int gj = jt * 64 + row;
      if (gj < Tn && cg < 6) {
        v1 = *reinterpret_cast<const u16x8*>(khb + (size_t)gj * 768 + hh1 * 48 + cg * 8);
        v2 = *reinterpret_cast<const u16x8*>(khb + (size_t)gj * 768 + hh2 * 48 + cg * 8);
      }
      *reinterpret_cast<u16x8*>(&K1s[row][cg * 8]) = v1;
      *reinterpret_cast<u16x8*>(&K2s[row][cg * 8]) = v2;
    }
    __syncthreads();
    f32x4 a1c[4] = {}, a2c[4] = {};
#pragma unroll
    for (int ks = 0; ks < 2; ks++) {
#pragma unroll
      for (int ni = 0; ni < 4; ni++) {
        bf16x8 b1 = *reinterpret_cast<const bf16x8*>(&K1s[ni * 16 + lrow][ks * 32 + lgrp * 8]);
        bf16x8 b2 = *reinterpret_cast<const bf16x8*>(&K2s[ni * 16 + lrow][ks * 32 + lgrp * 8]);
        a1c[ni] = __builtin_amdgcn_mfma_f32_16x16x32_bf16(qf1[ks], b1, a1c[ni], 0, 0, 0);
        a2c[ni] = __builtin_amdgcn_mfma_f32_16x16x32_bf16(qf2[ks], b2, a2c[ni], 0, 0, 0);
      }
    }
    int jbase = (jt * 64) % LPn;
#pragma unroll
    for (int r = 0; r < 4; r++) {
      int imod = imodr[r];
#pragma unroll
      for (int ni = 0; ni < 4; ni++) {
        int j = jt * 64 + ni * 16 + lrow;
        int jmod = jbase + ni * 16 + lrow;
        if (jmod >= LPn) jmod -= LPn;
        bool masked = (j >= Tn) || (jmod > imod);
        l1r[r] += fexp2((masked ? -1e9f : a1c[ni][r]) - MSHIFT);
        l2r[r] += fexp2((masked ? -1e9f : a2c[ni][r]) - MSHIFT);
      }
    }
  }
  // single end reduce over the 16 lrow lanes
#pragma unroll
  for (int r = 0; r < 4; r++) {
    for (int mk = 1; mk < 16; mk <<= 1) {
      l1r[r] += __shfl_xor(l1r[r], mk);
      l2r[r] += __shfl_xor(l2r[r], mk);
    }
  }
  if (lrow == 0) {
#pragma unroll
    for (int r = 0; r < 4; r++) {
      if (irow[r] < Tn) {
        lsum[(size_t)(hf * 16 + hh1) * TP + irow[r]] = l1r[r];
        lsum[(size_t)(hf * 16 + hh2) * TP + irow[r]] = l2r[r];
      }
    }
  }
}

// ---------------- attention pass 2 (li normalization, jt-split x6, Ps aliases K1s) ----------------
__global__ __launch_bounds__(256) void k_attn_pass2(const __hip_bfloat16* __restrict__ qhb,
                                                    const __hip_bfloat16* __restrict__ khb,
                                                    const __hip_bfloat16* __restrict__ vtb,
                                                    const float* __restrict__ lsum,
                                                    const float* __restrict__ lq1,
                                                    const float* __restrict__ lk1,
                                                    const float* __restrict__ lq2,
                                                    const float* __restrict__ lk2,
                                                    float lamc,
                                                    float* __restrict__ opv,
                                                    float* __restrict__ colsum_p) {
  __shared__ unsigned short K1s[64][68];   // Ps aliases this after score MFMAs
  __shared__ unsigned short K2s[64][68];
  __shared__ unsigned short Bv[64][68];
  unsigned short (*Ps)[68] = K1s;
  int bm = blockIdx.x * 64, p = blockIdx.y, hf = blockIdx.z;
  int jt0 = hf * 6, jt1 = min(33, jt0 + 6);
  int hh1 = 2 * p, hh2 = 2 * p + 1;
  float lam = calc_lam(lq1, lk1, lq2, lk2, lamc);
  int tid = threadIdx.x;
  int wave = tid >> 6, lane = tid & 63;
  int lrow = lane & 15, lgrp = lane >> 4;
  const unsigned short* vt = (const unsigned short*)vtb + (size_t)p * 64 * Tn;
  bf16x8 qf1[2], qf2[2];
  int qrow = bm + wave * 16 + lrow;
  load_qfrag(qhb, qrow, hh1, lgrp, qf1);
  load_qfrag(qhb, qrow, hh2, lgrp, qf2);
  // merge NQ pass1 quarters' l (plain sum; fixed shift)
  int irow[4], imodr[4]; float li1[4], li2[4];
#pragma unroll
  for (int r = 0; r < 4; r++) {
    irow[r] = bm + wave * 16 + lgrp * 4 + r;
    imodr[r] = irow[r] % LPn;
    if (irow[r] < Tn) {
      float l1 = 0.f, l2 = 0.f;
#pragma unroll
      for (int q = 0; q < NQ; q++) {
        l1 += lsum[(size_t)(q * 16 + hh1) * TP + irow[r]];
        l2 += lsum[(size_t)(q * 16 + hh2) * TP + irow[r]];
      }
      li1[r] = 1.f / l1; li2[r] = 1.f / l2;
    } else { li1[r] = 0.f; li2[r] = 0.f; }
  }
  f32x4 accpv[4] = {};
  for (int jt = jt0; jt < jt1; jt++) {
    if (tile_masked(bm, jt)) {
      colsum_p[((size_t)p * 132 + blockIdx.x * 4 + wave) * TP + jt * 64 + lgrp * 16 + lrow] = 0.f;
      continue;
    }
    __syncthreads();            // prior iter's Ps/Bv reads done
#pragma unroll
    for (int i = 0; i < 2; i++) {
      int vecIdx = tid + i * 256;
      int row = vecIdx >> 3, cg = vecIdx & 7;
      u16x8 v1 = {0, 0, 0, 0, 0, 0, 0, 0}, v2 = v1, vv = v1;
      int gj = jt * 64 + row;
      if (gj < Tn && cg < 6) {
        v1 = *reinterpret_cast<const u16x8*>(khb + (size_t)gj * 768 + hh1 * 48 + cg * 8);
        v2 = *reinterpret_cast<const u16x8*>(khb + (size_t)gj * 768 + hh2 * 48 + cg * 8);
      }
      int jc = jt * 64 + cg * 8;
      if (jc + 8 <= Tn)
        vv = *reinterpret_cast<const u16x8*>(vt + (size_t)row * Tn + jc);
      *reinterpret_cast<u16x8*>(&K1s[row][cg * 8]) = v1;
      *reinterpret_cast<u16x8*>(&K2s[row][cg * 8]) = v2;
      *reinterpret_cast<u16x8*>(&Bv[row][cg * 8]) = vv;
    }
    __syncthreads();
    f32x4 a1c[4] = {}, a2c[4] = {};
#pragma unroll
    for (int ks = 0; ks < 2; ks++) {
#pragma unroll
      for (int ni = 0; ni < 4; ni++) {
        bf16x8 b1 = *reinterpret_cast<const bf16x8*>(&K1s[ni * 16 + lrow][ks * 32 + lgrp * 8]);
        bf16x8 b2 = *reinterpret_cast<const bf16x8*>(&K2s[ni * 16 + lrow][ks * 32 + lgrp * 8]);
        a1c[ni] = __builtin_amdgcn_mfma_f32_16x16x32_bf16(qf1[ks], b1, a1c[ni], 0, 0, 0);
        a2c[ni] = __builtin_amdgcn_mfma_f32_16x16x32_bf16(qf2[ks], b2, a2c[ni], 0, 0, 0);
      }
    }
    __syncthreads();            // all K1s reads done before Ps (alias) writes
    int jbase = (jt * 64) % LPn;
    float cs[4];
#pragma unroll
    for (int ni = 0; ni < 4; ni++) cs[ni] = 0.f;
#pragma unroll
    for (int ni = 0; ni < 4; ni++) {
      int j = jt * 64 + ni * 16 + lrow;
      int jmod = jbase + ni * 16 + lrow;
      if (jmod >= LPn) jmod -= LPn;
      bool jok = (j < Tn);
#pragma unroll
      for (int r = 0; r < 4; r++) {
        bool masked = (!jok) || (jmod > imodr[r]);
        float sv1 = masked ? -1e9f : a1c[ni][r];
        float sv2 = masked ? -1e9f : a2c[ni][r];
        float a1 = fexp2(sv1 - MSHIFT) * li1[r];
        float a2 = fexp2(sv2 - MSHIFT) * li2[r];
        float c = fmaf(-lam, a2, a1);
        Ps[wave * 16 + lgrp * 4 + r][ni * 16 + lrow] = f2bu(c);
        cs[ni] += a1;
      }
    }
#pragma unroll
    for (int ni = 0; ni < 4; ni++) {
      cs[ni] += __shfl_xor(cs[ni], 16);
      cs[ni] += __shfl_xor(cs[ni], 32);
    }
    {
      float mine = (lgrp == 0) ? cs[0] : (lgrp == 1) ? cs[1] : (lgrp == 2) ? cs[2] : cs[3];
      colsum_p[((size_t)p * 132 + blockIdx.x * 4 + wave) * TP + jt * 64 + lgrp * 16 + lrow] = mine;
    }
    __syncthreads();            // Ps writes visible to all waves
#pragma unroll
    for (int ks = 0; ks < 2; ks++) {
      bf16x8 af = *reinterpret_cast<const bf16x8*>(&Ps[wave * 16 + lrow][ks * 32 + lgrp * 8]);
#pragma unroll
      for (int ni = 0; ni < 4; ni++) {
        bf16x8 bfr = *reinterpret_cast<const bf16x8*>(&Bv[ni * 16 + lrow][ks * 32 + lgrp * 8]);
        accpv[ni] = __builtin_amdgcn_mfma_f32_16x16x32_bf16(af, bfr, accpv[ni], 0, 0, 0);
      }
    }
  }
#pragma unroll
  for (int ni = 0; ni < 4; ni++)
#pragma unroll
    for (int r = 0; r < 4; r++) {
      int row = bm + wave * 16 + lgrp * 4 + r;
      int col = ni * 16 + lrow;
      if (row < Tn) opv[((size_t)(hf * 8 + p) * Tn + row) * 64 + col] = accpv[ni][r];
    }
}

// ---------------- batched gwv (4 waves/block): wave w -> p = by*4+w ----------------
__global__ __launch_bounds__(256) void k_gwv(const float* __restrict__ colsum_p,
                                             const __hip_bfloat16* __restrict__ vtb,
                                             const float* __restrict__ lq1,
                                             const float* __restrict__ lk1,
                                             const float* __restrict__ lq2,
                                             const float* __restrict__ lk2,
                                             float lamc,
                                             float* __restrict__ Wb) {
  int jmod = blockIdx.x;
  int p = blockIdx.y * 4 + (threadIdx.x >> 6);
  int l = threadIdx.x & 63;
  float lam = calc_lam(lq1, lk1, lq2, lk2, lamc);
  int k = l >> 3, sub = l & 7;
  int jk = jmod + 257 * k;
  float s = 0.f;
  for (int ib = sub; ib < 132; ib += 8) s += colsum_p[((size_t)p * 132 + ib) * TP + jk];
  for (int m = 1; m < 8; m <<= 1) s += __shfl_xor(s, m);
  float gv = s * (1.f / (float)Tn) * lam;
  const __hip_bfloat16* vrow = vtb + (size_t)(p * 64 + l) * Tn;
  float acc = 0.f;
#pragma unroll
  for (int kk = 0; kk < 8; kk++) {
    float gk = __shfl(gv, kk * 8);
    acc = fmaf(gk, __bfloat162float(vrow[jmod + 257 * kk]), acc);
  }
  Wb[((size_t)p * 257 + jmod) * 64 + l] = acc;
}

// ---------------- batched chunksum (4 waves/block) ----------------
__global__ __launch_bounds__(256) void k_chunksum(const float* __restrict__ Wb,
                                                  float* __restrict__ Cb) {
  int c = blockIdx.x;
  int p = blockIdx.y * 4 + (threadIdx.x >> 6);
  int lane = threadIdx.x & 63;
  int m0 = c * 16, m1 = min(m0 + 16, LPn);
  float acc = 0.f;
  for (int m = m0; m < m1; m++) acc += Wb[((size_t)p * 257 + m) * 64 + lane];
  Cb[((size_t)p * 17 + c) * 64 + lane] = acc;
}

// ---------------- pv_out: sum NQ opv parts + G-prefix + head-RMSNorm -> bf16 ----------------
__global__ __launch_bounds__(256) void k_pv_out(const float* __restrict__ opv,
                                                const float* __restrict__ Wb,
                                                const float* __restrict__ Cb,
                                                const float* __restrict__ hnw,
                                                __hip_bfloat16* __restrict__ onormb) {
  int w = threadIdx.x >> 6, lane = threadIdx.x & 63;
  int i = blockIdx.x * 4 + w;
  int p = blockIdx.y;
  int imod = i % LPn;
  int cidx = imod >> 4;
  float s = 0.f;
#pragma unroll
  for (int hf = 0; hf < NQ; hf++) s += opv[((size_t)(hf * 8 + p) * Tn + i) * 64 + lane];
  for (int c = 0; c < cidx; c++) s += Cb[((size_t)p * 17 + c) * 64 + lane];
  for (int m = cidx * 16; m <= imod; m++) s += Wb[((size_t)p * 257 + m) * 64 + lane];
  float ss = s * s;
  for (int off = 1; off < 64; off <<= 1) ss += __shfl_xor(ss, off);
  float scale = rsqrtf(ss * (1.f / 64.f) + 1e-5f);
  onormb[((size_t)p * Tn + i) * 64 + lane] = __float2bfloat16(s * scale * hnw[lane]);
}

// ---------------- final head (float32 out) ----------------
__global__ __launch_bounds__(192) void k_final(const float* __restrict__ z,
                                               const float* __restrict__ outW,
                                               float* __restrict__ out) {
  int t = blockIdx.x;
  int p = threadIdx.x >> 6, lane = threadIdx.x & 63;
  float acc = 0.f;
  for (int m = lane; m < 512; m += 64) acc = fmaf(z[(size_t)t * 512 + m], outW[(size_t)p * 512 + m], acc);
  for (int off = 1; off < 64; off <<= 1) acc += __shfl_xor(acc, off);
  if (lane == 0) out[(size_t)t * 3 + p] = acc;
}

extern "C" void kernel_launch(void* const* d_in, const int* in_sizes, int n_in,
                              void* d_out, int out_size, void* d_ws, size_t ws_size,
                              hipStream_t stream) {
  const float* x          = (const float*)d_in[0];
  const float* ticker_emb = (const float*)d_in[1];
  const float* sep_emb    = (const float*)d_in[2];
  const float* shared_W   = (const float*)d_in[3];
  const float* unique_W   = (const float*)d_in[4];
  const float* norm1_w    = (const float*)d_in[5];
  const float* norm2_w    = (const float*)d_in[6];
  const float* kv_down_W  = (const float*)d_in[7];
  const float* q_down_W   = (const float*)d_in[8];
  const float* kv_up_W    = (const float*)d_in[9];
  const float* q_up_W     = (const float*)d_in[10];
  const float* kv_norm_w  = (const float*)d_in[11];
  const float* q_norm_w   = (const float*)d_in[12];
  const float* o_W        = (const float*)d_in[13];
  const float* lam_q1     = (const float*)d_in[14];
  const float* lam_k1     = (const float*)d_in[15];
  const float* lam_q2     = (const float*)d_in[16];
  const float* lam_k2     = (const float*)d_in[17];
  const float* head_norm_w= (const float*)d_in[18];
  const float* ff_in_W    = (const float*)d_in[19];
  const float* ff_out_W   = (const float*)d_in[20];
  const float* final_norm = (const float*)d_in[21];
  const float* out_W      = (const float*)d_in[22];
  const int*   seperator  = (const int*)d_in[23];
  const int*   tickers    = (const int*)d_in[24];
  (void)in_sizes; (void)n_in;

  float* W = (float*)d_ws;
  size_t off = 0;
  auto alloc = [&](size_t n) { float* p = W + off; off += n; return p; };
  float* cosb  = alloc(2048);
  float* sinb  = alloc(2048);
  float* h     = alloc((size_t)Tn * Dn);
  float* xnb_f = alloc((size_t)Tn * 256);         // bf16 T x 512 (also z)
  float* ckv   = alloc((size_t)Tn * 160);         // ckv+qlat host onormb later
  float* qlat  = alloc((size_t)Tn * 192);
  float* ckvnb_f = alloc((size_t)Tn * 64);        // bf16 T x 128
  float* qlatnb_f = alloc((size_t)Tn * 96);       // bf16 T x 192
  float* kvb   = alloc((size_t)Tn * 1024);        // gatedb overlay
  float* qf    = alloc((size_t)Tn * 768);         // zfin overlay
  float* qhb_f = alloc((size_t)Tn * 384);         // bf16 T x 768
  float* khb_f = alloc((size_t)Tn * 384);         // bf16 T x 768
  float* vtb_f = alloc((size_t)Tn * 256);         // bf16 512 x T
  float* lsumb = alloc((size_t)(NQ * 16) * TP);   // [NQ quarters][16 heads][TP]
  float* colsum_p = alloc((size_t)8 * 132 * TP);
  float* Wb    = alloc((size_t)8 * 257 * 64);
  float* Cb    = alloc((size_t)8 * 17 * 64);
  float* pp    = alloc((size_t)NQ * Tn * 512);    // opv (NQ x 8 x T x 64) / GEMM partials
  float* wcvt_f = alloc((size_t)WP / 2);          // bf16 weight arena, one layer

  __hip_bfloat16* xnb    = (__hip_bfloat16*)xnb_f;
  __hip_bfloat16* ckvnb  = (__hip_bfloat16*)ckvnb_f;
  __hip_bfloat16* qlatnb = (__hip_bfloat16*)qlatnb_f;
  __hip_bfloat16* onormb = (__hip_bfloat16*)ckv;     // bf16 T x 512 over ckv+qlat
  __hip_bfloat16* gatedb = (__hip_bfloat16*)kvb;     // bf16 T x 2048
  __hip_bfloat16* qhb    = (__hip_bfloat16*)qhb_f;
  __hip_bfloat16* khb    = (__hip_bfloat16*)khb_f;
  __hip_bfloat16* vtb    = (__hip_bfloat16*)vtb_f;
  __hip_bfloat16* wcvt   = (__hip_bfloat16*)wcvt_f;
  float* opv   = pp;         // NQ x 8 x T x 64 f32 == NQ x T x 512 (disjoint lifetime)
  float* zfin  = qf;

  size_t needed = off * sizeof(float);            // ~77 MB (< 79.5 proven)
  if (ws_size < needed) {
    k_fill42<<<(out_size + 255) / 256, 256, 0, stream>>>((float*)d_out, out_size);
    return;
  }

  k_freqs<<<8, 256, 0, stream>>>(cosb, sinb);
  k_embed<<<dim3(Tn, 2), 256, 0, stream>>>(x, ticker_emb, sep_emb, shared_W, unique_W,
                                           seperator, tickers, h);
  // layer-0 pre-norm merged with layer-0 weight convert
  k_rms_cvt<<<Tn + CVB, 256, 0, stream>>>(h, norm1_w, xnb,
                                          kv_down_W, q_down_W, kv_up_W, q_up_W,
                                          o_W, ff_in_W, ff_out_W, wcvt);

  const __hip_bfloat16* wkvdqd = wcvt;            // 352 x 512 (kvd rows 0..159, qd rows 160..351)
  const __hip_bfloat16* wkvu   = wcvt + 180224;   // 1024 x 128
  const __hip_bfloat16* wqu    = wcvt + 311296;   // 768 x 192
  const __hip_bfloat16* woW    = wcvt + 458752;   // 512 x 512
  const __hip_bfloat16* wffi   = wcvt + 720896;   // 4096 x 512
  const __hip_bfloat16* wffo   = wcvt + 2818048;  // 512 x 2048

  for (int d = 0; d < 2; d++) {
    const float* n2   = norm2_w + d * 512;
    const float* kvnw = kv_norm_w + d * 128;
    const float* qnw  = q_norm_w + d * 192;
    const float* hnw  = head_norm_w + d * 64;
    float lamc = 0.8f - 0.6f * expf(-0.3f * (float)d);

    k_gemm64_dual<<<dim3(6, 33), 256, 0, stream>>>(xnb, wkvdqd, ckv, qlat);
    k_rmsnorm2_b<<<dim3(Tn / 4, 2), 256, 0, stream>>>(ckv, qlat, kvnw, qnw, ckvnb, qlatnb);
    // kvu-GEMM (N=1024,K=128) + qu-GEMM (N=768,K=192) merged into one launch
    k_gemm64_pair<<<dim3(16, 33, 2), 256, 0, stream>>>(ckvnb, wkvu, kvb, 1024, 128,
                                                       qlatnb, wqu, qf, 768, 192);
    // q/k assemble + V transpose merged into one launch
    k_qkv_vt<<<Tn + 264, 256, 0, stream>>>(qf, kvb, ckv, cosb, sinb, qhb, khb, vtb);

    k_attn_pass1<<<dim3(33, 8, NQ), 256, 0, stream>>>(qhb, khb, lsumb);
    k_attn_pass2<<<dim3(33, 8, NQ), 256, 0, stream>>>(qhb, khb, vtb, lsumb,
                                                      lam_q1 + d * 32, lam_k1 + d * 32,
                                                      lam_q2 + d * 32, lam_k2 + d * 32,
                                                      lamc, opv, colsum_p);
    k_gwv<<<dim3(257, 2), 256, 0, stream>>>(colsum_p, vtb,
                                            lam_q1 + d * 32, lam_k1 + d * 32,
                                            lam_q2 + d * 32, lam_k2 + d * 32,
                                            lamc, Wb);
    k_chunksum<<<dim3(17, 2), 256, 0, stream>>>(Wb, Cb);
    k_pv_out<<<dim3(514, 8), 256, 0, stream>>>(opv, Wb, Cb, hnw, onormb);

    // o-proj: K=512 split x2 -> partials -> fused h += & rmsnorm(n2) -> xnb
    k_gemm64p<<<dim3(8, 33, 2), 256, 0, stream>>>(onormb, woW, pp, Tn, 512, 256);
    k_addred_rms_b<<<Tn, 256, 0, stream>>>(h, pp, n2, xnb, 2);
    k_ffn<<<dim3(32, 17), 256, 0, stream>>>(xnb, wffi, gatedb);
    // ffo: K=2048 split x4 -> partials -> fused h += & next norm
    k_gemm64p<<<dim3(8, 33, 4), 256, 0, stream>>>(gatedb, wffo, pp, Tn, 512, 512);
    if (d == 0) {
      // h += ffn; xnb = rmsnorm(h, norm1_w[1]) ; convert layer-1 weights (arena now dead)
      k_addred_rms_cvt<<<Tn + CVB, 256, 0, stream>>>(h, pp, norm1_w + 512, xnb,
                                                     kv_down_W + 81920,  q_down_W + 98304,
                                                     kv_up_W   + 131072, q_up_W   + 147456,
                                                     o_W       + 262144, ff_in_W  + 2097152,
                                                     ff_out_W  + 1048576, wcvt);
    } else {
      // h += ffn; zfin = rmsnorm(h, final_norm) f32
      k_addred_rms_f<<<Tn, 256, 0, stream>>>(h, pp, final_norm, zfin, 4);
    }
  }

  k_final<<<Tn, 192, 0, stream>>>(zfin, out_W, (float*)d_out);
}

// Round 33
// 474.044 us; speedup vs baseline: 1.0134x; 1.0134x over previous
//
#include <hip/hip_runtime.h>
#include <hip/hip_bf16.h>

// Money_former MLA DINT — round 33: r32 base (480 us ~ best 479.7 within noise)
// + final riskless launch-merge: k_freqs absorbed into k_embed (grid Tn+8 x 2).
// T=2056, D=512, 2 layers, 16 logical heads (8 pairs) of 48.

#define Tn 2056
#define LPn 257
#define Dn 512
#define TP 2112   // padded T (33*64)
#define NQ 6      // jt quarters
#define WP 3866624  // weight params per layer (see cvtw segment map)
#define CVB 3776    // cvt blocks = WP/4/256

static constexpr float SC_LOG2E  = 0.20822625044783914f;   // 48^-0.5 * log2(e)
static constexpr float MSHIFT    = 32.0f;                  // fixed softmax shift (base-2)
static constexpr float EPS_C     = 1.1920928955078125e-07f;

typedef float f32x4 __attribute__((ext_vector_type(4)));
typedef short bf16x8 __attribute__((ext_vector_type(8)));
typedef unsigned short u16x8 __attribute__((ext_vector_type(8)));

__device__ __forceinline__ float fexp2(float x) { return __builtin_amdgcn_exp2f(x); }

__device__ __forceinline__ unsigned short f2bu(float f) {
  __hip_bfloat16 h = __float2bfloat16(f);
  return *reinterpret_cast<unsigned short*>(&h);
}

// fully-masked (i-block, j-tile) test: 64-run mod 257 min/max
__device__ __forceinline__ bool tile_masked(int bm, int jt) {
  int jstart = (jt * 64) % LPn;
  int jmin = (jstart + 63 >= LPn) ? 0 : jstart;
  int istart = bm % LPn;
  int imax = (istart + 63 >= LPn) ? (LPn - 1) : (istart + 63);
  return jmin > imax;
}

// per-block inline lambda
__device__ __forceinline__ float calc_lam(const float* lq1, const float* lk1,
                                          const float* lq2, const float* lk2,
                                          float lamc) {
  float d1 = 0.f, d2 = 0.f;
#pragma unroll
  for (int k = 0; k < 32; k++) { d1 = fmaf(lq1[k], lk1[k], d1); d2 = fmaf(lq2[k], lk2[k], d2); }
  return __expf(d1) - __expf(d2) + lamc;
}

// ---------------- weight convert body: 7 segments -> contiguous bf16 arena ----------------
// layout (elements): [kvd 160x512 | qd 192x512 | kvu 1024x128 | qu 768x192 |
//                     oW 512x512 | ffi 4096x512 | ffo 512x2048]
// boundaries: 81920, 180224, 311296, 458752, 720896, 2818048, 3866624 (=WP)
__device__ __forceinline__ void cvtw_body(int vid, int tid,
                                          const float* __restrict__ kvd,
                                          const float* __restrict__ qd,
                                          const float* __restrict__ kvu,
                                          const float* __restrict__ qu,
                                          const float* __restrict__ oW,
                                          const float* __restrict__ ffi,
                                          const float* __restrict__ ffo,
                                          __hip_bfloat16* __restrict__ out) {
  size_t i = ((size_t)vid * 256 + tid) * 4;
  if (i >= (size_t)WP) return;
  size_t r = i;
  const float* src;
  if      (r <   81920) { src = kvd + r; }
  else if (r <  180224) { src = qd  + (r - 81920); }
  else if (r <  311296) { src = kvu + (r - 180224); }
  else if (r <  458752) { src = qu  + (r - 311296); }
  else if (r <  720896) { src = oW  + (r - 458752); }
  else if (r < 2818048) { src = ffi + (r - 720896); }
  else                  { src = ffo + (r - 2818048); }
  f32x4 v = *reinterpret_cast<const f32x4*>(src);
  unsigned short o4[4];
#pragma unroll
  for (int e = 0; e < 4; e++) o4[e] = f2bu(v[e]);
  *reinterpret_cast<uint2*>((unsigned short*)out + i) = *reinterpret_cast<const uint2*>(o4);
}

// ---------------- sentinel ----------------
__global__ __launch_bounds__(256) void k_fill42(float* __restrict__ out, int n) {
  int i = blockIdx.x * 256 + threadIdx.x;
  if (i < n) out[i] = 42.0f;
}

// ---------------- Embedding (+ RoPE tables for x >= Tn, y == 0) ----------------
__global__ __launch_bounds__(256) void k_embed(const float* __restrict__ x,
                                               const float* __restrict__ ticker_emb,
                                               const float* __restrict__ sep_emb,
                                               const float* __restrict__ shared_W,
                                               const float* __restrict__ unique_W,
                                               const int* __restrict__ sep_idx,
                                               const int* __restrict__ tickers,
                                               float* __restrict__ h,
                                               float* __restrict__ cosb,
                                               float* __restrict__ sinb) {
  if (blockIdx.x >= Tn) {
    if (blockIdx.y == 0) {
      int idx = (blockIdx.x - Tn) * 256 + threadIdx.x;
      if (idx < 256 * 8) {
        int pos = idx >> 3, j = idx & 7;
        float fb = powf(10000.f, -(float)j * 0.125f);            // 1/10000^(j/8)
        float ramp = fminf(fmaxf((float)j * 0.25f, 0.f), 1.f);   // low=0, high=4
        float sm = 1.f - ramp;
        float fr = fb * (1.f / 40.f) * (1.f - sm) + fb * sm;
        float ang = (float)pos * fr;
        cosb[idx] = cosf(ang);
        sinb[idx] = sinf(ang);
      }
    }
    return;
  }
  int t = blockIdx.x;
  int c = blockIdx.y * 256 + threadIdx.x;
  int l = t >> 3, s = t & 7;
  float val;
  if (l == 0) {
    val = sep_emb[sep_idx[0] * Dn + c];
  } else {
    const float* xr = x + ((size_t)(l - 1) * 8 + s) * 32;
    const float* w = (c < 384) ? (shared_W + (size_t)c * 32)
                               : (unique_W + ((size_t)s * 128 + (c - 384)) * 32);
    float acc = 0.f;
#pragma unroll
    for (int f = 0; f < 32; f++) acc = fmaf(xr[f], w[f], acc);
    val = acc;
  }
  val += ticker_emb[(size_t)tickers[s] * Dn + c];
  h[(size_t)t * Dn + c] = val;
}

// ---------------- merged: x < Tn -> rmsnorm512 (h->xnb bf16) ; else -> cvtw ----------------
__global__ __launch_bounds__(256) void k_rms_cvt(const float* __restrict__ in,
                                                 const float* __restrict__ w,
                                                 __hip_bfloat16* __restrict__ out,
                                                 const float* __restrict__ kvd,
                                                 const float* __restrict__ qd,
                                                 const float* __restrict__ kvu,
                                                 const float* __restrict__ qu,
                                                 const float* __restrict__ oW,
                                                 const float* __restrict__ ffi,
                                                 const float* __restrict__ ffo,
                                                 __hip_bfloat16* __restrict__ wout) {
  __shared__ float red[4];
  if (blockIdx.x >= Tn) {
    cvtw_body(blockIdx.x - Tn, threadIdx.x, kvd, qd, kvu, qu, oW, ffi, ffo, wout);
    return;
  }
  int row = blockIdx.x;
  const float* xr = in + (size_t)row * 512;
  float ss = 0.f;
  for (int c = threadIdx.x; c < 512; c += 256) { float v = xr[c]; ss = fmaf(v, v, ss); }
  for (int off = 1; off < 64; off <<= 1) ss += __shfl_xor(ss, off);
  if ((threadIdx.x & 63) == 0) red[threadIdx.x >> 6] = ss;
  __syncthreads();
  float tot = red[0] + red[1] + red[2] + red[3];
  float scale = rsqrtf(tot * (1.f / 512.f) + EPS_C);
  for (int c = threadIdx.x; c < 512; c += 256)
    out[(size_t)row * 512 + c] = __float2bfloat16(xr[c] * scale * w[c]);
}

// ---------------- dual RMSNorm, wave-per-row: y==0 ckv(128,str160), y==1 qlat(192,str192) ----------------
__global__ __launch_bounds__(256) void k_rmsnorm2_b(const float* __restrict__ ckv,
                                                    const float* __restrict__ qlat,
                                                    const float* __restrict__ kvnw,
                                                    const float* __restrict__ qnw,
                                                    __hip_bfloat16* __restrict__ ckvnb,
                                                    __hip_bfloat16* __restrict__ qlatnb) {
  int wave = threadIdx.x >> 6, lane = threadIdx.x & 63;
  int row = blockIdx.x * 4 + wave;
  const float* xr; const float* w; __hip_bfloat16* out; int ncols;
  if (blockIdx.y == 0) { xr = ckv + (size_t)row * 160;  w = kvnw; out = ckvnb + (size_t)row * 128;  ncols = 128; }
  else                 { xr = qlat + (size_t)row * 192; w = qnw;  out = qlatnb + (size_t)row * 192; ncols = 192; }
  float ss = 0.f;
  for (int c = lane; c < ncols; c += 64) { float v = xr[c]; ss = fmaf(v, v, ss); }
  for (int off = 1; off < 64; off <<= 1) ss += __shfl_xor(ss, off);
  float scale = rsqrtf(ss / (float)ncols + EPS_C);
  for (int c = lane; c < ncols; c += 64)
    out[c] = __float2bfloat16(xr[c] * scale * w[c]);
}

// ---------------- fused: h += sum(pp parts) ; xnb = rmsnorm(h)*w (bf16 out) ----------------
__global__ __launch_bounds__(256) void k_addred_rms_b(float* __restrict__ h,
                                                      const float* __restrict__ pp,
                                                      const float* __restrict__ w,
                                                      __hip_bfloat16* __restrict__ out,
                                                      int nsplit) {
  int row = blockIdx.x;
  long n = (long)Tn * 512;
  float v[2];
  float ss = 0.f;
#pragma unroll
  for (int cc = 0; cc < 2; cc++) {
    int c = threadIdx.x + cc * 256;
    long idx = (long)row * 512 + c;
    float s = h[idx];
    for (int k = 0; k < nsplit; k++) s += pp[(size_t)k * n + idx];
    h[idx] = s;
    v[cc] = s;
    ss = fmaf(s, s, ss);
  }
  for (int off = 1; off < 64; off <<= 1) ss += __shfl_xor(ss, off);
  __shared__ float red[4];
  if ((threadIdx.x & 63) == 0) red[threadIdx.x >> 6] = ss;
  __syncthreads();
  float tot = red[0] + red[1] + red[2] + red[3];
  float scale = rsqrtf(tot * (1.f / 512.f) + EPS_C);
#pragma unroll
  for (int cc = 0; cc < 2; cc++) {
    int c = threadIdx.x + cc * 256;
    out[(size_t)row * 512 + c] = __float2bfloat16(v[cc] * scale * w[c]);
  }
}

// ---------------- merged: x < Tn -> addred_rms_b(nsplit=4) ; else -> cvtw (next layer) ----------------
__global__ __launch_bounds__(256) void k_addred_rms_cvt(float* __restrict__ h,
                                                        const float* __restrict__ pp,
                                                        const float* __restrict__ w,
                                                        __hip_bfloat16* __restrict__ out,
                                                        const float* __restrict__ kvd,
                                                        const float* __restrict__ qd,
                                                        const float* __restrict__ kvu,
                                                        const float* __restrict__ qu,
                                                        const float* __restrict__ oW,
                                                        const float* __restrict__ ffi,
                                                        const float* __restrict__ ffo,
                                                        __hip_bfloat16* __restrict__ wout) {
  __shared__ float red[4];
  if (blockIdx.x >= Tn) {
    cvtw_body(blockIdx.x - Tn, threadIdx.x, kvd, qd, kvu, qu, oW, ffi, ffo, wout);
    return;
  }
  int row = blockIdx.x;
  long n = (long)Tn * 512;
  float v[2];
  float ss = 0.f;
#pragma unroll
  for (int cc = 0; cc < 2; cc++) {
    int c = threadIdx.x + cc * 256;
    long idx = (long)row * 512 + c;
    float s = h[idx];
    for (int k = 0; k < 4; k++) s += pp[(size_t)k * n + idx];
    h[idx] = s;
    v[cc] = s;
    ss = fmaf(s, s, ss);
  }
  for (int off = 1; off < 64; off <<= 1) ss += __shfl_xor(ss, off);
  if ((threadIdx.x & 63) == 0) red[threadIdx.x >> 6] = ss;
  __syncthreads();
  float tot = red[0] + red[1] + red[2] + red[3];
  float scale = rsqrtf(tot * (1.f / 512.f) + EPS_C);
#pragma unroll
  for (int cc = 0; cc < 2; cc++) {
    int c = threadIdx.x + cc * 256;
    out[(size_t)row * 512 + c] = __float2bfloat16(v[cc] * scale * w[c]);
  }
}

// ---------------- fused: h += sum(pp parts) ; zfin = rmsnorm(h)*w (f32 out) ----------------
__global__ __launch_bounds__(256) void k_addred_rms_f(float* __restrict__ h,
                                                      const float* __restrict__ pp,
                                                      const float* __restrict__ w,
                                                      float* __restrict__ out,
                                                      int nsplit) {
  int row = blockIdx.x;
  long n = (long)Tn * 512;
  float v[2];
  float ss = 0.f;
#pragma unroll
  for (int cc = 0; cc < 2; cc++) {
    int c = threadIdx.x + cc * 256;
    long idx = (long)row * 512 + c;
    float s = h[idx];
    for (int k = 0; k < nsplit; k++) s += pp[(size_t)k * n + idx];
    h[idx] = s;
    v[cc] = s;
    ss = fmaf(s, s, ss);
  }
  for (int off = 1; off < 64; off <<= 1) ss += __shfl_xor(ss, off);
  __shared__ float red[4];
  if ((threadIdx.x & 63) == 0) red[threadIdx.x >> 6] = ss;
  __syncthreads();
  float tot = red[0] + red[1] + red[2] + red[3];
  float scale = rsqrtf(tot * (1.f / 512.f) + EPS_C);
#pragma unroll
  for (int cc = 0; cc < 2; cc++) {
    int c = threadIdx.x + cc * 256;
    out[(size_t)row * 512 + c] = v[cc] * scale * w[c];
  }
}

// ---------------- paired GEMM: z=0 (A0,B0,C0,N0,K0), z=1 (A1,B1,C1,N1,K1) ----------------
__global__ __launch_bounds__(256) void k_gemm64_pair(const __hip_bfloat16* __restrict__ A0,
                                                     const __hip_bfloat16* __restrict__ B0,
                                                     float* __restrict__ C0, int N0, int K0,
                                                     const __hip_bfloat16* __restrict__ A1,
                                                     const __hip_bfloat16* __restrict__ B1,
                                                     float* __restrict__ C1, int N1, int K1) {
  __shared__ unsigned short Als[64][40];
  __shared__ unsigned short Bls[64][40];
  const __hip_bfloat16* A; const __hip_bfloat16* B; float* C; int N, K;
  if (blockIdx.z == 0) { A = A0; B = B0; C = C0; N = N0; K = K0; }
  else                 { A = A1; B = B1; C = C1; N = N1; K = K1; }
  int bm = blockIdx.y * 64, bn = blockIdx.x * 64;
  if (bn >= N) return;                       // uniform per-block early exit
  int tid = threadIdx.x;
  int wave = tid >> 6, lane = tid & 63;
  int lrow = lane & 15, lgrp = lane >> 4;
  f32x4 acc[4] = {};
  for (int k0 = 0; k0 < K; k0 += 32) {
    {
      int row = tid >> 2, cg = tid & 3;
      u16x8 v = {0, 0, 0, 0, 0, 0, 0, 0};
      if (bm + row < Tn)
        v = *reinterpret_cast<const u16x8*>(A + (size_t)(bm + row) * K + k0 + cg * 8);
      *reinterpret_cast<u16x8*>(&Als[row][cg * 8]) = v;
    }
    {
      int row = tid >> 2, cg = tid & 3;
      u16x8 v = {0, 0, 0, 0, 0, 0, 0, 0};
      if (bn + row < N)
        v = *reinterpret_cast<const u16x8*>(B + (size_t)(bn + row) * K + k0 + cg * 8);
      *reinterpret_cast<u16x8*>(&Bls[row][cg * 8]) = v;
    }
    __syncthreads();
    bf16x8 af = *reinterpret_cast<const bf16x8*>(&Als[wave * 16 + lrow][lgrp * 8]);
    bf16x8 bfr[4];
#pragma unroll
    for (int ni = 0; ni < 4; ni++)
      bfr[ni] = *reinterpret_cast<const bf16x8*>(&Bls[ni * 16 + lrow][lgrp * 8]);
#pragma unroll
    for (int ni = 0; ni < 4; ni++)
      acc[ni] = __builtin_amdgcn_mfma_f32_16x16x32_bf16(af, bfr[ni], acc[ni], 0, 0, 0);
    __syncthreads();
  }
#pragma unroll
  for (int ni = 0; ni < 4; ni++)
#pragma unroll
    for (int r = 0; r < 4; r++) {
      int row = bm + wave * 16 + lgrp * 4 + r;
      int col = bn + ni * 16 + lrow;
      if (row < Tn && col < N)
        C[(size_t)row * N + col] = acc[ni][r];
    }
}

// ---------------- dual GEMM: [ckv | qlat] = xnb @ (wkvd||wqd)^T, N=352, K=512 ----------------
__global__ __launch_bounds__(256) void k_gemm64_dual(const __hip_bfloat16* __restrict__ A,
                                                     const __hip_bfloat16* __restrict__ B,
                                                     float* __restrict__ ckv,
                                                     float* __restrict__ qlat) {
  __shared__ unsigned short Als[64][40];
  __shared__ unsigned short Bls[64][40];
  int bm = blockIdx.y * 64, bn = blockIdx.x * 64;
  int tid = threadIdx.x;
  int wave = tid >> 6, lane = tid & 63;
  int lrow = lane & 15, lgrp = lane >> 4;
  f32x4 acc[4] = {};
  for (int k0 = 0; k0 < 512; k0 += 32) {
    {
      int row = tid >> 2, cg = tid & 3;
      u16x8 v = {0, 0, 0, 0, 0, 0, 0, 0};
      if (bm + row < Tn)
        v = *reinterpret_cast<const u16x8*>(A + (size_t)(bm + row) * 512 + k0 + cg * 8);
      *reinterpret_cast<u16x8*>(&Als[row][cg * 8]) = v;
    }
    {
      int row = tid >> 2, cg = tid & 3;
      u16x8 v = {0, 0, 0, 0, 0, 0, 0, 0};
      if (bn + row < 352)
        v = *reinterpret_cast<const u16x8*>(B + (size_t)(bn + row) * 512 + k0 + cg * 8);
      *reinterpret_cast<u16x8*>(&Bls[row][cg * 8]) = v;
    }
    __syncthreads();
    bf16x8 af = *reinterpret_cast<const bf16x8*>(&Als[wave * 16 + lrow][lgrp * 8]);
    bf16x8 bfr[4];
#pragma unroll
    for (int ni = 0; ni < 4; ni++)
      bfr[ni] = *reinterpret_cast<const bf16x8*>(&Bls[ni * 16 + lrow][lgrp * 8]);
#pragma unroll
    for (int ni = 0; ni < 4; ni++)
      acc[ni] = __builtin_amdgcn_mfma_f32_16x16x32_bf16(af, bfr[ni], acc[ni], 0, 0, 0);
    __syncthreads();
  }
#pragma unroll
  for (int ni = 0; ni < 4; ni++)
#pragma unroll
    for (int r = 0; r < 4; r++) {
      int row = bm + wave * 16 + lgrp * 4 + r;
      int col = bn + ni * 16 + lrow;
      if (row < Tn) {
        if (col < 160)      ckv [(size_t)row * 160 + col]         = acc[ni][r];
        else if (col < 352) qlat[(size_t)row * 192 + (col - 160)] = acc[ni][r];
      }
    }
}

// ---------------- K-split 64x64 MFMA GEMM -> partial buffer pp[kc] (bf16 B) ----------------
__global__ __launch_bounds__(256) void k_gemm64p(const __hip_bfloat16* __restrict__ A,
                                                 const __hip_bfloat16* __restrict__ B,
                                                 float* __restrict__ pp,
                                                 int M, int N, int kchunk) {
  __shared__ unsigned short Als[64][40];
  __shared__ unsigned short Bls[64][40];
  int bm = blockIdx.y * 64, bn = blockIdx.x * 64;
  int kc = blockIdx.z;
  int K = kchunk * gridDim.z;
  int kbase = kc * kchunk;
  int tid = threadIdx.x;
  int wave = tid >> 6, lane = tid & 63;
  int lrow = lane & 15, lgrp = lane >> 4;
  f32x4 acc[4] = {};
  for (int k0 = kbase; k0 < kbase + kchunk; k0 += 32) {
    {
      int row = tid >> 2, cg = tid & 3;
      u16x8 v = {0, 0, 0, 0, 0, 0, 0, 0};
      if (bm + row < M)
        v = *reinterpret_cast<const u16x8*>(A + (size_t)(bm + row) * K + k0 + cg * 8);
      *reinterpret_cast<u16x8*>(&Als[row][cg * 8]) = v;
    }
    {
      int row = tid >> 2, cg = tid & 3;
      u16x8 v = {0, 0, 0, 0, 0, 0, 0, 0};
      if (bn + row < N)
        v = *reinterpret_cast<const u16x8*>(B + (size_t)(bn + row) * K + k0 + cg * 8);
      *reinterpret_cast<u16x8*>(&Bls[row][cg * 8]) = v;
    }
    __syncthreads();
    bf16x8 af = *reinterpret_cast<const bf16x8*>(&Als[wave * 16 + lrow][lgrp * 8]);
    bf16x8 bfr[4];
#pragma unroll
    for (int ni = 0; ni < 4; ni++)
      bfr[ni] = *reinterpret_cast<const bf16x8*>(&Bls[ni * 16 + lrow][lgrp * 8]);
#pragma unroll
    for (int ni = 0; ni < 4; ni++)
      acc[ni] = __builtin_amdgcn_mfma_f32_16x16x32_bf16(af, bfr[ni], acc[ni], 0, 0, 0);
    __syncthreads();
  }
#pragma unroll
  for (int ni = 0; ni < 4; ni++)
#pragma unroll
    for (int r = 0; r < 4; r++) {
      int row = bm + wave * 16 + lgrp * 4 + r;
      int col = bn + ni * 16 + lrow;
      if (row < M && col < N)
        pp[(size_t)kc * M * N + (size_t)row * N + col] = acc[ni][r];
    }
}

// ---------------- Fused FFN-in + SwiGLU (bf16 B) ----------------
__global__ __launch_bounds__(256) void k_ffn(const __hip_bfloat16* __restrict__ A,
                                             const __hip_bfloat16* __restrict__ Bw,
                                             __hip_bfloat16* __restrict__ gatedb) {
  __shared__ unsigned short Als[128][40];
  __shared__ unsigned short Bls[128][40];
  int bm = blockIdx.y * 128, bn = blockIdx.x * 64;
  int tid = threadIdx.x;
  int wave = tid >> 6, lane = tid & 63;
  int lrow = lane & 15, lgrp = lane >> 4;
  f32x4 acc[2][8] = {};
  for (int k0 = 0; k0 < 512; k0 += 32) {
#pragma unroll
    for (int i = 0; i < 2; i++) {
      int vecIdx = tid + i * 256;
      int row = vecIdx >> 2, cg = vecIdx & 3;
      u16x8 v = {0, 0, 0, 0, 0, 0, 0, 0};
      if (bm + row < Tn)
        v = *reinterpret_cast<const u16x8*>(A + (size_t)(bm + row) * 512 + k0 + cg * 8);
      *reinterpret_cast<u16x8*>(&Als[row][cg * 8]) = v;
    }
#pragma unroll
    for (int i = 0; i < 2; i++) {
      int vecIdx = tid + i * 256;
      int row = vecIdx >> 2, cg = vecIdx & 3;
      int grow = (row < 64) ? (bn + row) : (2048 + bn + (row - 64));
      u16x8 v = *reinterpret_cast<const u16x8*>(Bw + (size_t)grow * 512 + k0 + cg * 8);
      *reinterpret_cast<u16x8*>(&Bls[row][cg * 8]) = v;
    }
    __syncthreads();
    bf16x8 af[2], bfr[8];
#pragma unroll
    for (int mi = 0; mi < 2; mi++)
      af[mi] = *reinterpret_cast<const bf16x8*>(&Als[wave * 32 + mi * 16 + lrow][lgrp * 8]);
#pragma unroll
    for (int ni = 0; ni < 8; ni++)
      bfr[ni] = *reinterpret_cast<const bf16x8*>(&Bls[ni * 16 + lrow][lgrp * 8]);
#pragma unroll
    for (int mi = 0; mi < 2; mi++)
#pragma unroll
      for (int ni = 0; ni < 8; ni++)
        acc[mi][ni] = __builtin_amdgcn_mfma_f32_16x16x32_bf16(af[mi], bfr[ni], acc[mi][ni], 0, 0, 0);
    __syncthreads();
  }
#pragma unroll
  for (int mi = 0; mi < 2; mi++)
#pragma unroll
    for (int ni = 0; ni < 4; ni++)
#pragma unroll
      for (int r = 0; r < 4; r++) {
        int row = bm + wave * 32 + mi * 16 + lgrp * 4 + r;
        int col = bn + ni * 16 + lrow;
        if (row < Tn) {
          float u = acc[mi][ni][r];
          float vv = acc[mi][ni + 4][r];
          float sv = vv / (1.f + __expf(-vv));
          gatedb[(size_t)row * 2048 + col] = __float2bfloat16(u * sv);
        }
      }
}

// ---------------- merged: x < Tn -> q/k assemble ; else -> V transpose ----------------
__global__ __launch_bounds__(256) void k_qkv_vt(const float* __restrict__ qf,
                                                const float* __restrict__ kvb,
                                                const float* __restrict__ ckv,
                                                const float* __restrict__ cosb,
                                                const float* __restrict__ sinb,
                                                __hip_bfloat16* __restrict__ qhb,
                                                __hip_bfloat16* __restrict__ khb,
                                                __hip_bfloat16* __restrict__ vtb) {
  __shared__ float tile[64][65];
  if (blockIdx.x < Tn) {
    // ---- q/k assemble (partial RoPE, bf16 out); q pre-scaled ----
    int t = blockIdx.x;
    int l = t >> 3;
    for (int idx = threadIdx.x; idx < 768; idx += 256) {
      int hh = idx / 48, dc = idx % 48;
      int hd = hh >> 1, e = hh & 1;
      float qv, kvv;
      if (dc < 32) {
        qv  = qf [(size_t)t * 768  + hd * 96  + e * 32 + dc];
        kvv = kvb[(size_t)t * 1024 + hd * 128 + e * 32 + dc];
      } else {
        int rj = dc - 32;            // 0..15
        int p = rj >> 1; int isim = rj & 1;
        float xr_q = qf[(size_t)t * 768 + hd * 96 + 64 + e * 16 + p * 2];
        float xi_q = qf[(size_t)t * 768 + hd * 96 + 64 + e * 16 + p * 2 + 1];
        float xr_k = ckv[(size_t)t * 160 + 128 + e * 16 + p * 2];
        float xi_k = ckv[(size_t)t * 160 + 128 + e * 16 + p * 2 + 1];
        if (l == 0) {
          qv  = isim ? xi_q : xr_q;
          kvv = isim ? xi_k : xr_k;
        } else {
          float c = cosb[(l - 1) * 8 + p], s = sinb[(l - 1) * 8 + p];
          if (!isim) { qv = xr_q * c - xi_q * s; kvv = xr_k * c - xi_k * s; }
          else       { qv = xr_q * s + xi_q * c; kvv = xr_k * s + xi_k * c; }
        }
      }
      qhb[(size_t)t * 768 + idx] = __float2bfloat16(qv * SC_LOG2E);   // fold scaling*log2e
      khb[(size_t)t * 768 + idx] = __float2bfloat16(kvv);
    }
  } else {
    // ---- V transpose: vtb[c][t] bf16 ----
    int vid = blockIdx.x - Tn;     // 0..263
    int tt = vid % 33, ct = vid / 33;
    int tid = threadIdx.x;
#pragma unroll
    for (int rep = 0; rep < 16; rep++) {
      int idx = rep * 256 + tid;
      int tr = idx >> 6, cc = idx & 63;
      int t = tt * 64 + tr;
      tile[tr][cc] = (t < Tn) ? kvb[(size_t)t * 1024 + ct * 128 + 64 + cc] : 0.f;
    }
    __syncthreads();
#pragma unroll
    for (int rep = 0; rep < 16; rep++) {
      int idx = rep * 256 + tid;
      int cr = idx >> 6, tc = idx & 63;
      int t = tt * 64 + tc;
      if (t < Tn)
        vtb[(size_t)(ct * 64 + cr) * Tn + t] = __float2bfloat16(tile[tc][cr]);
    }
  }
}

// ---------------- load one Q fragment pair from global (pad cols >=48 are 0) ----------------
__device__ __forceinline__ void load_qfrag(const __hip_bfloat16* qhb, int qrow, int hh,
                                           int lgrp, bf16x8* qf) {
#pragma unroll
  for (int ks = 0; ks < 2; ks++) {
    int co = ks * 32 + lgrp * 8;
    bf16x8 v = {0, 0, 0, 0, 0, 0, 0, 0};
    if (qrow < Tn && co < 48)
      v = *reinterpret_cast<const bf16x8*>(qhb + (size_t)qrow * 768 + hh * 48 + co);
    qf[ks] = v;
  }
}

// ---------------- attention pass 1: per-lane l-sum, single end reduce ----------------
// grid (33, 8, NQ). lsum[(hf*16+hh)*TP + i] = sum_j 2^(s_ij - 32) over this quarter.
__global__ __launch_bounds__(256) void k_attn_pass1(const __hip_bfloat16* __restrict__ qhb,
                                                    const __hip_bfloat16* __restrict__ khb,
                                                    float* __restrict__ lsum) {
  __shared__ unsigned short K1s[64][68];
  __shared__ unsigned short K2s[64][68];
  int bm = blockIdx.x * 64, p = blockIdx.y, hf = blockIdx.z;
  int jt0 = hf * 6, jt1 = min(33, jt0 + 6);
  int hh1 = 2 * p, hh2 = 2 * p + 1;
  int tid = threadIdx.x;
  int wave = tid >> 6, lane = tid & 63;
  int lrow = lane & 15, lgrp = lane >> 4;
  bf16x8 qf1[2], qf2[2];
  int qrow = bm + wave * 16 + lrow;
  load_qfrag(qhb, qrow, hh1, lgrp, qf1);
  load_qfrag(qhb, qrow, hh2, lgrp, qf2);
  float l1r[4], l2r[4];
  int irow[4], imodr[4];
#pragma unroll
  for (int r = 0; r < 4; r++) {
    l1r[r] = 0.f; l2r[r] = 0.f;
    irow[r] = bm + wave * 16 + lgrp * 4 + r;
    imodr[r] = irow[r] % LPn;
  }

  for (int jt = jt0; jt < jt1; jt++) {
    if (tile_masked(bm, jt)) continue;
    __syncthreads();
#pragma unroll
    for (int i = 0; i < 2; i++) {
      int vecIdx = tid + i * 256;
      int row = vecIdx >> 3, cg = vecIdx & 7;
      u16x8 v1 = {0, 0, 0, 0, 0, 0, 0, 0}, v2 = v1;
      int gj = jt * 64 + row;
      if (gj < Tn && cg < 6) {
        v1 = *reinterpret_cast<const u16x8*>(khb + (size_t)gj * 768 + hh1 * 48 + cg * 8);
        v2 = *reinterpret_cast<const u16x8*>(khb + (size_t)gj * 768 + hh2 * 48 + cg * 8);
      }
      *reinterpret_cast<u16x8*>(&K1s[row][cg * 8]) = v1;
      *reinterpret_cast<u16x8*>(&K2s[row][cg * 8]) = v2;
    }
    __syncthreads();
    f32x4 a1c[4] = {}, a2c[4] = {};
#pragma unroll
    for (int ks = 0; ks < 2; ks++) {
#pragma unroll
      for (int ni = 0; ni < 4; ni++) {
        bf16x8 b1 = *reinterpret_cast<const bf16x8*>(&K1s[ni * 16 + lrow][ks * 32 + lgrp * 8]);
        bf16x8 b2 = *reinterpret_cast<const bf16x8*>(&K2s[ni * 16 + lrow][ks * 32 + lgrp * 8]);
        a1c[ni] = __builtin_amdgcn_mfma_f32_16x16x32_bf16(qf1[ks], b1, a1c[ni], 0, 0, 0);
        a2c[ni] = __builtin_amdgcn_mfma_f32_16x16x32_bf16(qf2[ks], b2, a2c[ni], 0, 0, 0);
      }
    }
    int jbase = (jt * 64) % LPn;
#pragma unroll
    for (int r = 0; r < 4; r++) {
      int imod = imodr[r];
#pragma unroll
      for (int ni = 0; ni < 4; ni++) {
        int j = jt * 64 + ni * 16 + lrow;
        int jmod = jbase + ni * 16 + lrow;
        if (jmod >= LPn) jmod -= LPn;
        bool masked = (j >= Tn) || (jmod > imod);
        l1r[r] += fexp2((masked ? -1e9f : a1c[ni][r]) - MSHIFT);
        l2r[r] += fexp2((masked ? -1e9f : a2c[ni][r]) - MSHIFT);
      }
    }
  }
  // single end reduce over the 16 lrow lanes
#pragma unroll
  for (int r = 0; r < 4; r++) {
    for (int mk = 1; mk < 16; mk <<= 1) {
      l1r[r] += __shfl_xor(l1r[r], mk);
      l2r[r] += __shfl_xor(l2r[r], mk);
    }
  }
  if (lrow == 0) {
#pragma unroll
    for (int r = 0; r < 4; r++) {
      if (irow[r] < Tn) {
        lsum[(size_t)(hf * 16 + hh1) * TP + irow[r]] = l1r[r];
        lsum[(size_t)(hf * 16 + hh2) * TP + irow[r]] = l2r[r];
      }
    }
  }
}

// ---------------- attention pass 2 (li normalization, jt-split x6, Ps aliases K1s) ----------------
__global__ __launch_bounds__(256) void k_attn_pass2(const __hip_bfloat16* __restrict__ qhb,
                                                    const __hip_bfloat16* __restrict__ khb,
                                                    const __hip_bfloat16* __restrict__ vtb,
                                                    const float* __restrict__ lsum,
                                                    const float* __restrict__ lq1,
                                                    const float* __restrict__ lk1,
                                                    const float* __restrict__ lq2,
                                                    const float* __restrict__ lk2,
                                                    float lamc,
                                                    float* __restrict__ opv,
                                                    float* __restrict__ colsum_p) {
  __shared__ unsigned short K1s[64][68];   // Ps aliases this after score MFMAs
  __shared__ unsigned short K2s[64][68];
  __shared__ unsigned short Bv[64][68];
  unsigned short (*Ps)[68] = K1s;
  int bm = blockIdx.x * 64, p = blockIdx.y, hf = blockIdx.z;
  int jt0 = hf * 6, jt1 = min(33, jt0 + 6);
  int hh1 = 2 * p, hh2 = 2 * p + 1;
  float lam = calc_lam(lq1, lk1, lq2, lk2, lamc);
  int tid = threadIdx.x;
  int wave = tid >> 6, lane = tid & 63;
  int lrow = lane & 15, lgrp = lane >> 4;
  const unsigned short* vt = (const unsigned short*)vtb + (size_t)p * 64 * Tn;
  bf16x8 qf1[2], qf2[2];
  int qrow = bm + wave * 16 + lrow;
  load_qfrag(qhb, qrow, hh1, lgrp, qf1);
  load_qfrag(qhb, qrow, hh2, lgrp, qf2);
  // merge NQ pass1 quarters' l (plain sum; fixed shift)
  int irow[4], imodr[4]; float li1[4], li2[4];
#pragma unroll
  for (int r = 0; r < 4; r++) {
    irow[r] = bm + wave * 16 + lgrp * 4 + r;
    imodr[r] = irow[r] % LPn;
    if (irow[r] < Tn) {
      float l1 = 0.f, l2 = 0.f;
#pragma unroll
      for (int q = 0; q < NQ; q++) {
        l1 += lsum[(size_t)(q * 16 + hh1) * TP + irow[r]];
        l2 += lsum[(size_t)(q * 16 + hh2) * TP + irow[r]];
      }
      li1[r] = 1.f / l1; li2[r] = 1.f / l2;
    } else { li1[r] = 0.f; li2[r] = 0.f; }
  }
  f32x4 accpv[4] = {};
  for (int jt = jt0; jt < jt1; jt++) {
    if (tile_masked(bm, jt)) {
      colsum_p[((size_t)p * 132 + blockIdx.x * 4 + wave) * TP + jt * 64 + lgrp * 16 + lrow] = 0.f;
      continue;
    }
    __syncthreads();            // prior iter's Ps/Bv reads done
#pragma unroll
    for (int i = 0; i < 2; i++) {
      int vecIdx = tid + i * 256;
      int row = vecIdx >> 3, cg = vecIdx & 7;
      u16x8 v1 = {0, 0, 0, 0, 0, 0, 0, 0}, v2 = v1, vv = v1;
      int gj = jt * 64 + row;
      if (gj < Tn && cg < 6) {
        v1 = *reinterpret_cast<const u16x8*>(khb + (size_t)gj * 768 + hh1 * 48 + cg * 8);
        v2 = *reinterpret_cast<const u16x8*>(khb + (size_t)gj * 768 + hh2 * 48 + cg * 8);
      }
      int jc = jt * 64 + cg * 8;
      if (jc + 8 <= Tn)
        vv = *reinterpret_cast<const u16x8*>(vt + (size_t)row * Tn + jc);
      *reinterpret_cast<u16x8*>(&K1s[row][cg * 8]) = v1;
      *reinterpret_cast<u16x8*>(&K2s[row][cg * 8]) = v2;
      *reinterpret_cast<u16x8*>(&Bv[row][cg * 8]) = vv;
    }
    __syncthreads();
    f32x4 a1c[4] = {}, a2c[4] = {};
#pragma unroll
    for (int ks = 0; ks < 2; ks++) {
#pragma unroll
      for (int ni = 0; ni < 4; ni++) {
        bf16x8 b1 = *reinterpret_cast<const bf16x8*>(&K1s[ni * 16 + lrow][ks * 32 + lgrp * 8]);
        bf16x8 b2 = *reinterpret_cast<const bf16x8*>(&K2s[ni * 16 + lrow][ks * 32 + lgrp * 8]);
        a1c[ni] = __builtin_amdgcn_mfma_f32_16x16x32_bf16(qf1[ks], b1, a1c[ni], 0, 0, 0);
        a2c[ni] = __builtin_amdgcn_mfma_f32_16x16x32_bf16(qf2[ks], b2, a2c[ni], 0, 0, 0);
      }
    }
    __syncthreads();            // all K1s reads done before Ps (alias) writes
    int jbase = (jt * 64) % LPn;
    float cs[4];
#pragma unroll
    for (int ni = 0; ni < 4; ni++) cs[ni] = 0.f;
#pragma unroll
    for (int ni = 0; ni < 4; ni++) {
      int j = jt * 64 + ni * 16 + lrow;
      int jmod = jbase + ni * 16 + lrow;
      if (jmod >= LPn) jmod -= LPn;
      bool jok = (j < Tn);
#pragma unroll
      for (int r = 0; r < 4; r++) {
        bool masked = (!jok) || (jmod > imodr[r]);
        float sv1 = masked ? -1e9f : a1c[ni][r];
        float sv2 = masked ? -1e9f : a2c[ni][r];
        float a1 = fexp2(sv1 - MSHIFT) * li1[r];
        float a2 = fexp2(sv2 - MSHIFT) * li2[r];
        float c = fmaf(-lam, a2, a1);
        Ps[wave * 16 + lgrp * 4 + r][ni * 16 + lrow] = f2bu(c);
        cs[ni] += a1;
      }
    }
#pragma unroll
    for (int ni = 0; ni < 4; ni++) {
      cs[ni] += __shfl_xor(cs[ni], 16);
      cs[ni] += __shfl_xor(cs[ni], 32);
    }
    {
      float mine = (lgrp == 0) ? cs[0] : (lgrp == 1) ? cs[1] : (lgrp == 2) ? cs[2] : cs[3];
      colsum_p[((size_t)p * 132 + blockIdx.x * 4 + wave) * TP + jt * 64 + lgrp * 16 + lrow] = mine;
    }
    __syncthreads();            // Ps writes visible to all waves
#pragma unroll
    for (int ks = 0; ks < 2; ks++) {
      bf16x8 af = *reinterpret_cast<const bf16x8*>(&Ps[wave * 16 + lrow][ks * 32 + lgrp * 8]);
#pragma unroll
      for (int ni = 0; ni < 4; ni++) {
        bf16x8 bfr = *reinterpret_cast<const bf16x8*>(&Bv[ni * 16 + lrow][ks * 32 + lgrp * 8]);
        accpv[ni] = __builtin_amdgcn_mfma_f32_16x16x32_bf16(af, bfr, accpv[ni], 0, 0, 0);
      }
    }
  }
#pragma unroll
  for (int ni = 0; ni < 4; ni++)
#pragma unroll
    for (int r = 0; r < 4; r++) {
      int row = bm + wave * 16 + lgrp * 4 + r;
      int col = ni * 16 + lrow;
      if (row < Tn) opv[((size_t)(hf * 8 + p) * Tn + row) * 64 + col] = accpv[ni][r];
    }
}

// ---------------- batched gwv (4 waves/block): wave w -> p = by*4+w ----------------
__global__ __launch_bounds__(256) void k_gwv(const float* __restrict__ colsum_p,
                                             const __hip_bfloat16* __restrict__ vtb,
                                             const float* __restrict__ lq1,
                                             const float* __restrict__ lk1,
                                             const float* __restrict__ lq2,
                                             const float* __restrict__ lk2,
                                             float lamc,
                                             float* __restrict__ Wb) {
  int jmod = blockIdx.x;
  int p = blockIdx.y * 4 + (threadIdx.x >> 6);
  int l = threadIdx.x & 63;
  float lam = calc_lam(lq1, lk1, lq2, lk2, lamc);
  int k = l >> 3, sub = l & 7;
  int jk = jmod + 257 * k;
  float s = 0.f;
  for (int ib = sub; ib < 132; ib += 8) s += colsum_p[((size_t)p * 132 + ib) * TP + jk];
  for (int m = 1; m < 8; m <<= 1) s += __shfl_xor(s, m);
  float gv = s * (1.f / (float)Tn) * lam;
  const __hip_bfloat16* vrow = vtb + (size_t)(p * 64 + l) * Tn;
  float acc = 0.f;
#pragma unroll
  for (int kk = 0; kk < 8; kk++) {
    float gk = __shfl(gv, kk * 8);
    acc = fmaf(gk, __bfloat162float(vrow[jmod + 257 * kk]), acc);
  }
  Wb[((size_t)p * 257 + jmod) * 64 + l] = acc;
}

// ---------------- batched chunksum (4 waves/block) ----------------
__global__ __launch_bounds__(256) void k_chunksum(const float* __restrict__ Wb,
                                                  float* __restrict__ Cb) {
  int c = blockIdx.x;
  int p = blockIdx.y * 4 + (threadIdx.x >> 6);
  int lane = threadIdx.x & 63;
  int m0 = c * 16, m1 = min(m0 + 16, LPn);
  float acc = 0.f;
  for (int m = m0; m < m1; m++) acc += Wb[((size_t)p * 257 + m) * 64 + lane];
  Cb[((size_t)p * 17 + c) * 64 + lane] = acc;
}

// ---------------- pv_out: sum NQ opv parts + G-prefix + head-RMSNorm -> bf16 ----------------
__global__ __launch_bounds__(256) void k_pv_out(const float* __restrict__ opv,
                                                const float* __restrict__ Wb,
                                                const float* __restrict__ Cb,
                                                const float* __restrict__ hnw,
                                                __hip_bfloat16* __restrict__ onormb) {
  int w = threadIdx.x >> 6, lane = threadIdx.x & 63;
  int i = blockIdx.x * 4 + w;
  int p = blockIdx.y;
  int imod = i % LPn;
  int cidx = imod >> 4;
  float s = 0.f;
#pragma unroll
  for (int hf = 0; hf < NQ; hf++) s += opv[((size_t)(hf * 8 + p) * Tn + i) * 64 + lane];
  for (int c = 0; c < cidx; c++) s += Cb[((size_t)p * 17 + c) * 64 + lane];
  for (int m = cidx * 16; m <= imod; m++) s += Wb[((size_t)p * 257 + m) * 64 + lane];
  float ss = s * s;
  for (int off = 1; off < 64; off <<= 1) ss += __shfl_xor(ss, off);
  float scale = rsqrtf(ss * (1.f / 64.f) + 1e-5f);
  onormb[((size_t)p * Tn + i) * 64 + lane] = __float2bfloat16(s * scale * hnw[lane]);
}

// ---------------- final head (float32 out) ----------------
__global__ __launch_bounds__(192) void k_final(const float* __restrict__ z,
                                               const float* __restrict__ outW,
                                               float* __restrict__ out) {
  int t = blockIdx.x;
  int p = threadIdx.x >> 6, lane = threadIdx.x & 63;
  float acc = 0.f;
  for (int m = lane; m < 512; m += 64) acc = fmaf(z[(size_t)t * 512 + m], outW[(size_t)p * 512 + m], acc);
  for (int off = 1; off < 64; off <<= 1) acc += __shfl_xor(acc, off);
  if (lane == 0) out[(size_t)t * 3 + p] = acc;
}

extern "C" void kernel_launch(void* const* d_in, const int* in_sizes, int n_in,
                              void* d_out, int out_size, void* d_ws, size_t ws_size,
                              hipStream_t stream) {
  const float* x          = (const float*)d_in[0];
  const float* ticker_emb = (const float*)d_in[1];
  const float* sep_emb    = (const float*)d_in[2];
  const float* shared_W   = (const float*)d_in[3];
  const float* unique_W   = (const float*)d_in[4];
  const float* norm1_w    = (const float*)d_in[5];
  const float* norm2_w    = (const float*)d_in[6];
  const float* kv_down_W  = (const float*)d_in[7];
  const float* q_down_W   = (const float*)d_in[8];
  const float* kv_up_W    = (const float*)d_in[9];
  const float* q_up_W     = (const float*)d_in[10];
  const float* kv_norm_w  = (const float*)d_in[11];
  const float* q_norm_w   = (const float*)d_in[12];
  const float* o_W        = (const float*)d_in[13];
  const float* lam_q1     = (const float*)d_in[14];
  const float* lam_k1     = (const float*)d_in[15];
  const float* lam_q2     = (const float*)d_in[16];
  const float* lam_k2     = (const float*)d_in[17];
  const float* head_norm_w= (const float*)d_in[18];
  const float* ff_in_W    = (const float*)d_in[19];
  const float* ff_out_W   = (const float*)d_in[20];
  const float* final_norm = (const float*)d_in[21];
  const float* out_W      = (const float*)d_in[22];
  const int*   seperator  = (const int*)d_in[23];
  const int*   tickers    = (const int*)d_in[24];
  (void)in_sizes; (void)n_in;

  float* W = (float*)d_ws;
  size_t off = 0;
  auto alloc = [&](size_t n) { float* p = W + off; off += n; return p; };
  float* cosb  = alloc(2048);
  float* sinb  = alloc(2048);
  float* h     = alloc((size_t)Tn * Dn);
  float* xnb_f = alloc((size_t)Tn * 256);         // bf16 T x 512 (also z)
  float* ckv   = alloc((size_t)Tn * 160);         // ckv+qlat host onormb later
  float* qlat  = alloc((size_t)Tn * 192);
  float* ckvnb_f = alloc((size_t)Tn * 64);        // bf16 T x 128
  float* qlatnb_f = alloc((size_t)Tn * 96);       // bf16 T x 192
  float* kvb   = alloc((size_t)Tn * 1024);        // gatedb overlay
  float* qf    = alloc((size_t)Tn * 768);         // zfin overlay
  float* qhb_f = alloc((size_t)Tn * 384);         // bf16 T x 768
  float* khb_f = alloc((size_t)Tn * 384);         // bf16 T x 768
  float* vtb_f = alloc((size_t)Tn * 256);         // bf16 512 x T
  float* lsumb = alloc((size_t)(NQ * 16) * TP);   // [NQ quarters][16 heads][TP]
  float* colsum_p = alloc((size_t)8 * 132 * TP);
  float* Wb    = alloc((size_t)8 * 257 * 64);
  float* Cb    = alloc((size_t)8 * 17 * 64);
  float* pp    = alloc((size_t)NQ * Tn * 512);    // opv (NQ x 8 x T x 64) / GEMM partials
  float* wcvt_f = alloc((size_t)WP / 2);          // bf16 weight arena, one layer

  __hip_bfloat16* xnb    = (__hip_bfloat16*)xnb_f;
  __hip_bfloat16* ckvnb  = (__hip_bfloat16*)ckvnb_f;
  __hip_bfloat16* qlatnb = (__hip_bfloat16*)qlatnb_f;
  __hip_bfloat16* onormb = (__hip_bfloat16*)ckv;     // bf16 T x 512 over ckv+qlat
  __hip_bfloat16* gatedb = (__hip_bfloat16*)kvb;     // bf16 T x 2048
  __hip_bfloat16* qhb    = (__hip_bfloat16*)qhb_f;
  __hip_bfloat16* khb    = (__hip_bfloat16*)khb_f;
  __hip_bfloat16* vtb    = (__hip_bfloat16*)vtb_f;
  __hip_bfloat16* wcvt   = (__hip_bfloat16*)wcvt_f;
  float* opv   = pp;         // NQ x 8 x T x 64 f32 == NQ x T x 512 (disjoint lifetime)
  float* zfin  = qf;

  size_t needed = off * sizeof(float);            // ~77 MB (< 79.5 proven)
  if (ws_size < needed) {
    k_fill42<<<(out_size + 255) / 256, 256, 0, stream>>>((float*)d_out, out_size);
    return;
  }

  // embedding + RoPE tables in one launch
  k_embed<<<dim3(Tn + 8, 2), 256, 0, stream>>>(x, ticker_emb, sep_emb, shared_W, unique_W,
                                               seperator, tickers, h, cosb, sinb);
  // layer-0 pre-norm merged with layer-0 weight convert
  k_rms_cvt<<<Tn + CVB, 256, 0, stream>>>(h, norm1_w, xnb,
                                          kv_down_W, q_down_W, kv_up_W, q_up_W,
                                          o_W, ff_in_W, ff_out_W, wcvt);

  const __hip_bfloat16* wkvdqd = wcvt;            // 352 x 512 (kvd rows 0..159, qd rows 160..351)
  const __hip_bfloat16* wkvu   = wcvt + 180224;   // 1024 x 128
  const __hip_bfloat16* wqu    = wcvt + 311296;   // 768 x 192
  const __hip_bfloat16* woW    = wcvt + 458752;   // 512 x 512
  const __hip_bfloat16* wffi   = wcvt + 720896;   // 4096 x 512
  const __hip_bfloat16* wffo   = wcvt + 2818048;  // 512 x 2048

  for (int d = 0; d < 2; d++) {
    const float* n2   = norm2_w + d * 512;
    const float* kvnw = kv_norm_w + d * 128;
    const float* qnw  = q_norm_w + d * 192;
    const float* hnw  = head_norm_w + d * 64;
    float lamc = 0.8f - 0.6f * expf(-0.3f * (float)d);

    k_gemm64_dual<<<dim3(6, 33), 256, 0, stream>>>(xnb, wkvdqd, ckv, qlat);
    k_rmsnorm2_b<<<dim3(Tn / 4, 2), 256, 0, stream>>>(ckv, qlat, kvnw, qnw, ckvnb, qlatnb);
    // kvu-GEMM (N=1024,K=128) + qu-GEMM (N=768,K=192) merged into one launch
    k_gemm64_pair<<<dim3(16, 33, 2), 256, 0, stream>>>(ckvnb, wkvu, kvb, 1024, 128,
                                                       qlatnb, wqu, qf, 768, 192);
    // q/k assemble + V transpose merged into one launch
    k_qkv_vt<<<Tn + 264, 256, 0, stream>>>(qf, kvb, ckv, cosb, sinb, qhb, khb, vtb);

    k_attn_pass1<<<dim3(33, 8, NQ), 256, 0, stream>>>(qhb, khb, lsumb);
    k_attn_pass2<<<dim3(33, 8, NQ), 256, 0, stream>>>(qhb, khb, vtb, lsumb,
                                                      lam_q1 + d * 32, lam_k1 + d * 32,
                                                      lam_q2 + d * 32, lam_k2 + d * 32,
                                                      lamc, opv, colsum_p);
    k_gwv<<<dim3(257, 2), 256, 0, stream>>>(colsum_p, vtb,
                                            lam_q1 + d * 32, lam_k1 + d * 32,
                                            lam_q2 + d * 32, lam_k2 + d * 32,
                                            lamc, Wb);
    k_chunksum<<<dim3(17, 2), 256, 0, stream>>>(Wb, Cb);
    k_pv_out<<<dim3(514, 8), 256, 0, stream>>>(opv, Wb, Cb, hnw, onormb);

    // o-proj: K=512 split x2 -> partials -> fused h += & rmsnorm(n2) -> xnb
    k_gemm64p<<<dim3(8, 33, 2), 256, 0, stream>>>(onormb, woW, pp, Tn, 512, 256);
    k_addred_rms_b<<<Tn, 256, 0, stream>>>(h, pp, n2, xnb, 2);
    k_ffn<<<dim3(32, 17), 256, 0, stream>>>(xnb, wffi, gatedb);
    // ffo: K=2048 split x4 -> partials -> fused h += & next norm
    k_gemm64p<<<dim3(8, 33, 4), 256, 0, stream>>>(gatedb, wffo, pp, Tn, 512, 512);
    if (d == 0) {
      // h += ffn; xnb = rmsnorm(h, norm1_w[1]) ; convert layer-1 weights (arena now dead)
      k_addred_rms_cvt<<<Tn + CVB, 256, 0, stream>>>(h, pp, norm1_w + 512, xnb,
                                                     kv_down_W + 81920,  q_down_W + 98304,
                                                     kv_up_W   + 131072, q_up_W   + 147456,
                                                     o_W       + 262144, ff_in_W  + 2097152,
                                                     ff_out_W  + 1048576, wcvt);
    } else {
      // h += ffn; zfin = rmsnorm(h, final_norm) f32
      k_addred_rms_f<<<Tn, 256, 0, stream>>>(h, pp, final_norm, zfin, 4);
    }
  }

  k_final<<<Tn, 192, 0, stream>>>(zfin, out_W, (float*)d_out);
}